// Round 15
// baseline (417.107 us; speedup 1.0000x reference)
//
#include <hip/hip_runtime.h>
#include <hip/hip_bf16.h>
#include <math.h>

#define DEV __device__ __forceinline__

static constexpr int HW  = 4096;    // H*W
static constexpr int POS = 8192;    // B*H*W
static constexpr int SLAB = 6 * 64 * 4096;  // one ki-slab (floats)
static constexpr int TAILB = 512;   // tail_k grid (co-residency: 6 blk/CU * 256 CU = 1536 >= 512)

typedef __attribute__((ext_vector_type(8)))  short short8;
typedef __attribute__((ext_vector_type(16))) float floatx16;
typedef __attribute__((ext_vector_type(4)))  unsigned int uint4v;

// ---------- B-spline basis (order 3); constant denominators -> mul by recip ----------
template<int G>
DEV void bsplines(float x, float* out /* G+3 values */) {
  const float h = 2.0f / (float)G;
  float knot[G + 7];
#pragma unroll
  for (int t = 0; t < G + 7; ++t) knot[t] = -1.0f + (float)(t - 3) * h;
  float bb[G + 6];
#pragma unroll
  for (int t = 0; t < G + 6; ++t) bb[t] = (x >= knot[t] && x < knot[t + 1]) ? 1.0f : 0.0f;
#pragma unroll
  for (int j = 1; j <= 3; ++j) {
    const float inv = (float)G / (2.0f * (float)j);   // 1/(j*h), compile-time
#pragma unroll
    for (int t = 0; t < G + 6 - j; ++t) {
      float left  = (x - knot[t]) * inv;
      float right = (knot[t + j + 1] - x) * inv;
      bb[t] = left * bb[t] + right * bb[t + 1];
    }
  }
#pragma unroll
  for (int t = 0; t < G + 3; ++t) out[t] = bb[t];
}

DEV float sigmoidf_(float x) { return 1.0f / (1.0f + __expf(-x)); }

DEV float block_reduce_256(float v, float* sb) {  // blockDim.x == 256
  __syncthreads();
#pragma unroll
  for (int off = 32; off > 0; off >>= 1) v += __shfl_down(v, off, 64);
  int lane = threadIdx.x & 63, wid = threadIdx.x >> 6;
  if (lane == 0) sb[wid] = v;
  __syncthreads();
  return sb[0] + sb[1] + sb[2] + sb[3];
}

// ---------- software grid barrier, v2b ----------
// R11: RMW poll thrashed the line (~50us/barrier). v2: relaxed AGENT-scope
// atomic-load poll (no ownership) + s_sleep backoff. v2b (R14): BOUNDED spin
// (2^17 iters ~ 110ms >> legit wait ~100us) so a broken barrier produces a
// detectable wrong answer (passed=false) instead of a hung container --
// disambiguates kernel-hang from infra failure.
DEV void gbar(int* bar, int nb) {
  __syncthreads();
  if (threadIdx.x == 0) {
    __threadfence();
    __hip_atomic_fetch_add(bar, 1, __ATOMIC_RELEASE, __HIP_MEMORY_SCOPE_AGENT);
    for (int it = 0;
         __hip_atomic_load(bar, __ATOMIC_RELAXED, __HIP_MEMORY_SCOPE_AGENT) < nb
         && it < (1 << 17); ++it)
      __builtin_amdgcn_s_sleep(32);
    __threadfence();
  }
  __syncthreads();
}

// ================= prep bodies =================
// Fragment-major layouts (R5, proven):
//   W'[tap][s][half][lane*8]   (per tap: s<KC/16, 1024 elem per s)
//   F'[b][hs][s][wp][16]       (per row: s-major, 16 k per wp)

template<int CF>
DEV void wprep_body(const float* __restrict__ base_w, const float* __restrict__ spline_w,
                    __hip_bfloat16* __restrict__ Wt, int bid) {
  constexpr int KC = 64 * CF;
  int lin = bid * 256 + threadIdx.x;  // (tap, o, ic), 9*64*KC exact
  int ic = lin % KC;
  int rest = lin / KC;
  int o = rest & 63, tap = rest >> 6;
  int c = ic % CF, i = ic / CF;
  float v = (c == 0) ? base_w[(o * 64 + i) * 9 + tap]
                     : spline_w[((o * 64 + i) * 9 + tap) * (CF - 1) + (c - 1)];
  // fragment-major: s = ic>>4, kk = ic&15, q = kk>>3, r = kk&7, h = o>>5
  int s = ic >> 4, kk = ic & 15, q = kk >> 3, r = kk & 7, hh = o >> 5;
  int l = q * 32 + (o & 31);
  Wt[(size_t)tap * (64 * KC) + s * 1024 + hh * 512 + l * 8 + r] = __float2bfloat16(v);
}

template<int G>
DEV void c0r_body(int ki, const float* __restrict__ sw, float* __restrict__ out,
                  float* shmem /* >=256 floats */) {
  constexpr int NB = G + 3;
  int o = threadIdx.x & 63, part = threadIdx.x >> 6;  // 4 parts over i
  float b0[NB];
  bsplines<G>(0.0f, b0);
  float s = 0.0f;
  for (int kj = 0; kj < 3; ++kj) {
    int tap = ki * 3 + kj;
    for (int i = part * 16; i < part * 16 + 16; ++i) {
      const float* p = sw + ((size_t)(o * 64 + i) * 9 + tap) * NB;
#pragma unroll
      for (int c = 0; c < NB; ++c) s += p[c] * b0[c];
    }
  }
  shmem[part * 64 + o] = s;
  __syncthreads();
  if (part == 0)
    out[ki * 64 + o] = shmem[o] + shmem[64 + o] + shmem[128 + o] + shmem[192 + o];
}

// ---- merged interior features: one x load feeds all 3 branches ----
template<int G, int RB>
DEV void feat_stage(float xv, float s, __hip_bfloat16* lds, int ws, int i) {
  constexpr int CF = G + 4;
  constexpr int RS = 64 * CF + 16;    // padded region stride (bf16)
  float bas[G + 3];
  bsplines<G>(xv, bas);
  __hip_bfloat16* d = lds + RB + ws * RS + i * CF;
  d[0] = __float2bfloat16(s);
#pragma unroll
  for (int c = 1; c < CF; ++c) d[c] = __float2bfloat16(bas[c - 1]);
}

template<int CF, int D, int RBu>
DEV void feat_copy(__hip_bfloat16* __restrict__ F, int b, int h, int wg, const uint4v* l) {
  constexpr int WP = 64 + 2 * D;
  constexpr int KC = 64 * CF;
  uint4v* g = (uint4v*)(F + (size_t)(b * 64 + h) * WP * KC);
  for (int t = threadIdx.x; t < 32 * CF; t += 256) {
    int sc = t >> 3, r = t & 7, wl = r >> 1, k4 = r & 1;
    g[(size_t)(sc * WP + D + wg * 4 + wl) * 2 + k4] = l[RBu + wl * (8 * CF + 2) + sc * 2 + k4];
  }
}

DEV void feat_interior(const float* __restrict__ x, __hip_bfloat16* F0, __hip_bfloat16* F1,
                       __hip_bfloat16* F2, int bid, __hip_bfloat16* lds) {
  int tid = threadIdx.x;
  int ws = tid & 3, i = tid >> 2;
  int wg = bid & 15, h = (bid >> 4) & 63, b = bid >> 10;
  int w = wg * 4 + ws;
  float xv = x[((size_t)(b * 64 + i) * 64 + h) * 64 + w];   // always in-bounds
  float s = xv * sigmoidf_(xv);
  feat_stage<3, 0>(xv, s, lds, ws, i);      // CF=7,  RS=464
  feat_stage<6, 1856>(xv, s, lds, ws, i);   // CF=10, RS=656
  feat_stage<9, 4480>(xv, s, lds, ws, i);   // CF=13, RS=848
  __syncthreads();
  const uint4v* l = (const uint4v*)lds;
  feat_copy<7, 6, 0>(F0, b, h, wg, l);
  feat_copy<10, 12, 232>(F1, b, h, wg, l);
  feat_copy<13, 18, 560>(F2, b, h, wg, l);
}

// ---- constant halo fill: features of x=0 at wp in [0,D) u [64+D,WP) ----
template<int G, int D>
DEV void halo_body(__hip_bfloat16* __restrict__ F, int bidl, __hip_bfloat16* ldsb) {
  constexpr int CF = G + 4;
  constexpr int WP = 64 + 2 * D;
  constexpr int KC = 64 * CF;
  constexpr int PW = 8 * CF;      // uint4 per (row, halo-wp)
  constexpr int D2 = 2 * D;
  int tid = threadIdx.x;
  float bas0[G + 3];
  bsplines<G>(0.0f, bas0);        // bitwise-identical to interior xv=0 path
  for (int k = tid; k < KC; k += 256) {
    int c = k % CF;
    float v = 0.0f;               // c==0: silu(0)=0
#pragma unroll
    for (int cc = 1; cc < CF; ++cc) v = (c == cc) ? bas0[cc - 1] : v;
    ldsb[k] = __float2bfloat16(v);
  }
  __syncthreads();
  const uint4v* l = (const uint4v*)ldsb;
  uint4v* g = (uint4v*)F;
#pragma unroll
  for (int u = 0; u < 16; ++u) {
    int t = bidl * 4096 + u * 256 + tid;
    int rw = t / PW, r2 = t - rw * PW;
    int sc = r2 >> 1, k4 = r2 & 1;
    int row = rw / D2, wj = rw - row * D2;
    int wp = (wj < D) ? wj : 64 + wj;
    g[(size_t)row * (WP * KC / 8) + (size_t)(sc * WP + wp) * 2 + k4] = l[sc * 2 + k4];
  }
}

// ========== merged prep + features (data-independent, disjoint bid ranges) ==========
__global__ void prepfeat_k(const float* __restrict__ x,
                           __hip_bfloat16* F0, __hip_bfloat16* F1, __hip_bfloat16* F2,
                           const float* bw0, const float* sw0, const float* bw1,
                           const float* sw1, const float* bw2, const float* sw2,
                           __hip_bfloat16* W0, __hip_bfloat16* W1, __hip_bfloat16* W2,
                           float* C0r, const float* fuse_w, float* fwT,
                           float* xm, float* accz /* 1024 floats incl. barrier ctrs */) {
  __shared__ uint4v ldsq[984];                  // 3 regions: 4*(464+656+848) bf16 = 15744B
  __shared__ float shmem[256];                  // prep reductions
  __hip_bfloat16* lds = (__hip_bfloat16*)ldsq;
  int bid = blockIdx.x, tid = threadIdx.x;
  if (bid < 2048)      { feat_interior(x, F0, F1, F2, bid, lds); return; }
  else if (bid < 2069) { halo_body<3, 6>(F0, bid - 2048, lds); return; }   // 21 blocks
  else if (bid < 2129) { halo_body<6, 12>(F1, bid - 2069, lds); return; }  // 60 blocks
  else if (bid < 2246) { halo_body<9, 18>(F2, bid - 2129, lds); return; }  // 117 blocks
  int pb = bid - 2246;                          // [0, 4506) prep blocks
  if (pb < 1008)      { wprep_body<7>(bw0, sw0, W0, pb); }
  else if (pb < 2448) { wprep_body<10>(bw1, sw1, W1, pb - 1008); }
  else if (pb < 4320) { wprep_body<13>(bw2, sw2, W2, pb - 2448); }
  else if (pb < 4329) {
    int idx = pb - 4320, br = idx / 3, ki = idx % 3;
    if (br == 0)      c0r_body<3>(ki, sw0, C0r, shmem);
    else if (br == 1) c0r_body<6>(ki, sw1, C0r + 192, shmem);
    else              c0r_body<9>(ki, sw2, C0r + 384, shmem);
  } else if (pb < 4377) {  // fuse_w transpose (branch part)
    int lin = (pb - 4329) * 256 + tid;  // [0, 12288)
    int o = lin & 63, i2 = lin >> 6;
    fwT[i2 * 64 + o] = fuse_w[o * 256 + i2];
  } else if (pb < 4505) {  // x mean per (b,i)
    int bi = pb - 4377;
    const float* p = x + (size_t)bi * HW;
    float s = 0.0f;
    for (int t = tid; t < HW; t += 256) s += p[t];
    s = block_reduce_256(s, shmem);
    if (tid == 0) xm[bi] = s * (1.0f / HW);
  } else {  // zero: fstat[128]|bnacc_s[192]|bnacc_q[192]|se_acc[384]|bars[4]+pad
    for (int t = tid; t < 1024; t += 256) accz[t] = 0.0f;
  }
}

// ============ KAN conv: R7 ki-centric (proven 44us) — byte-identical ============
DEV floatx16 mfma_bf16(short8 a, short8 b, floatx16 c) {
  return __builtin_amdgcn_mfma_f32_32x32x16_bf16(a, b, c, 0, 0, 0);
}

template<int CF, int DD>
DEV void conv_dev(int ki, int b, int hp, const short* __restrict__ F,
                  const short* __restrict__ W, const float* __restrict__ C0r,
                  float* __restrict__ ypart, int br, float* __restrict__ red) {
  constexpr int KC = 64 * CF;
  constexpr int WP = 64 + 2 * DD;
  int wid = threadIdx.x >> 6;       // 0..5
  int wv  = wid & 1;                // source-row select
  int kjw = wid >> 1;               // kj tap owned by this wave
  int lane = threadIdx.x & 63;
  int lr = lane & 31, lq = lane >> 5;
  int hs = hp * 2 + wv;             // source row (always valid)
  int h_out = hs - (ki - 1) * DD;   // output row this source feeds for this ki
  bool valid = (h_out >= 0 && h_out < 64);
  int h_tgt = valid ? h_out : (h_out < 0 ? h_out + 64 : h_out - 64);  // mirror: C0 rows
  float* yb = ypart + (size_t)ki * SLAB + ((size_t)((br * 2 + b) * 64 + h_tgt)) * 4096;

  floatx16 acc[2][2];
#pragma unroll
  for (int ot = 0; ot < 2; ++ot)
#pragma unroll
    for (int wh = 0; wh < 2; ++wh)
#pragma unroll
      for (int r = 0; r < 16; ++r) acc[ot][wh][r] = 0.0f;

  if (valid) {
    // fragment-major bases: every load is base + s*const + lane-contiguous 16B
    const short* wl_ = W + (size_t)(ki * 3 + kjw) * (64 * KC) + lane * 8;
    const short* fB  = F + (size_t)(b * 64 + hs) * WP * KC
                         + (kjw * DD + lr) * 16 + lq * 8;
#pragma unroll 4
    for (int s = 0; s < 4 * CF; ++s) {   // 16-K per step
      short8 a0 = *(const short8*)(wl_ + s * 1024);
      short8 a1 = *(const short8*)(wl_ + s * 1024 + 512);
      short8 b0 = *(const short8*)(fB + s * (WP * 16));
      short8 b1 = *(const short8*)(fB + s * (WP * 16) + 512);
      acc[0][0] = mfma_bf16(a0, b0, acc[0][0]);
      acc[0][1] = mfma_bf16(a0, b1, acc[0][1]);
      acc[1][0] = mfma_bf16(a1, b0, acc[1][0]);
      acc[1][1] = mfma_bf16(a1, b1, acc[1][1]);
    }
  }

  // ---- reduce the 3 kj partials through LDS (stride 65: conflict-free) ----
  float* slot = red + (size_t)wv * (64 * 65) + lane * 65;
  if (kjw == 2 && valid) {
#pragma unroll
    for (int ot = 0; ot < 2; ++ot)
#pragma unroll
      for (int wh = 0; wh < 2; ++wh)
#pragma unroll
        for (int r = 0; r < 16; ++r) slot[(ot * 2 + wh) * 16 + r] = acc[ot][wh][r];
  }
  __syncthreads();
  if (kjw == 1 && valid) {
#pragma unroll
    for (int ot = 0; ot < 2; ++ot)
#pragma unroll
      for (int wh = 0; wh < 2; ++wh)
#pragma unroll
        for (int r = 0; r < 16; ++r) {
          int idx = (ot * 2 + wh) * 16 + r;
          slot[idx] += acc[ot][wh][r];
        }
  }
  __syncthreads();
  if (kjw != 0) return;

  if (!valid) {  // paired output row's source is OOB: constant C0 contribution
    const float* c0 = C0r + (br * 3 + ki) * 64;
#pragma unroll
    for (int wh = 0; wh < 2; ++wh) {
      int w = wh * 32 + lr;
#pragma unroll
      for (int ot = 0; ot < 2; ++ot)
#pragma unroll
        for (int r = 0; r < 16; ++r) {
          int o = (r & 3) + 8 * (r >> 2) + 4 * lq + 32 * ot;
          yb[(size_t)o * 64 + w] = c0[o];
        }
    }
    return;
  }

#pragma unroll
  for (int ot = 0; ot < 2; ++ot)
#pragma unroll
    for (int wh = 0; wh < 2; ++wh) {
      int w = wh * 32 + lr;
#pragma unroll
      for (int r = 0; r < 16; ++r) {
        int o = (r & 3) + 8 * (r >> 2) + 4 * lq + 32 * ot;
        yb[(size_t)o * 64 + w] = acc[ot][wh][r] + slot[(ot * 2 + wh) * 16 + r];
      }
    }
}

__global__ __launch_bounds__(384) void conv_all_k(
    const short* __restrict__ F0, const short* __restrict__ F1, const short* __restrict__ F2,
    const short* __restrict__ W0, const short* __restrict__ W1, const short* __restrict__ W2,
    const float* __restrict__ C0r, float* __restrict__ ypart) {
  __shared__ float red[2 * 64 * 65];    // 33.3 KB partial-acc reduction buffer
  // XCD swizzle: ki-siblings at bid, bid+8, bid+16 -> same XCD (bid % 8 fixed)
  int bid = blockIdx.x;                 // [0,576)
  int e  = bid & 7;
  int t  = bid >> 3;                    // [0,72)
  int ki = t % 3;
  int m  = (t / 3) * 8 + e;             // [0,192) combo (br,b,hp)
  int br = m >> 6, b = (m >> 5) & 1, hp = m & 31;
  if (br == 0)      conv_dev<7, 6>(ki, b, hp, F0, W0, C0r, ypart, 0, red);
  else if (br == 1) conv_dev<10, 12>(ki, b, hp, F1, W1, C0r, ypart, 1, red);
  else              conv_dev<13, 18>(ki, b, hp, F2, W2, C0r, ypart, 2, red);
}

// ============ fused tail (plain launch + software grid barrier v2b) ============
// phases: rb -> sesum -> semlp -> fuse -> final; bodies verbatim from the
// proven 6-kernel pipeline. 26.4KB LDS -> 6 blocks/CU -> all 512 co-resident.
__global__ __launch_bounds__(256) void tail_k(
    float* __restrict__ yp, float* __restrict__ bnacc_s, float* __restrict__ bnacc_q,
    const float* g0, const float* b0p, const float* g1, const float* b1p,
    const float* g2, const float* b2p,
    const float* w10, const float* w11, const float* w12,
    const float* w20, const float* w21, const float* w22,
    float* __restrict__ A1, float* __restrict__ A0,
    const float* xm, const float* gw, const float* gb,
    const float* bng, const float* bnb,
    const float* gpw1, const float* gpw2,
    const float* fuse_w, float* __restrict__ fgp,
    const float* __restrict__ fwT, const float* fb,
    float* __restrict__ tmp, float* __restrict__ fstat,
    float* __restrict__ se_acc, int* __restrict__ bars,
    const float* fbn_g, const float* fbn_b, float* __restrict__ out) {
  __shared__ float As[64][32];
  __shared__ float Ws[64][64];
  __shared__ float sm[64];
  __shared__ float g0s[2][64], gp1s[2][64], gpvs[2][64];
  int tid = threadIdx.x;

  // ---- phase 0: sum 3 ki-slabs into slab0 + atomic BN partials (old rb_k) ----
  for (int u = blockIdx.x; u < 1536; u += gridDim.x) {
    int bb = u / 256, chunk = u % 256;
    int br = bb >> 1;
    size_t base = (size_t)bb * 262144 + chunk * 1024 + tid * 4;
    float4 v = *(const float4*)(yp + base);
#pragma unroll
    for (int s2 = 1; s2 < 3; ++s2) {
      float4 u2 = *(const float4*)(yp + base + (size_t)s2 * SLAB);
      v.x += u2.x; v.y += u2.y; v.z += u2.z; v.w += u2.w;
    }
    *(float4*)(yp + base) = v;
    float s = v.x + v.y + v.z + v.w;
    float q = v.x * v.x + v.y * v.y + v.z * v.z + v.w * v.w;
    s += __shfl_down(s, 8, 16); s += __shfl_down(s, 4, 16);
    s += __shfl_down(s, 2, 16); s += __shfl_down(s, 1, 16);
    q += __shfl_down(q, 8, 16); q += __shfl_down(q, 4, 16);
    q += __shfl_down(q, 2, 16); q += __shfl_down(q, 1, 16);
    if ((tid & 15) == 0) {
      int o = (chunk * 16 + (tid >> 4)) & 63;
      atomicAdd(&bnacc_s[br * 64 + o], s);
      atomicAdd(&bnacc_q[br * 64 + o], q);
    }
  }
  gbar(&bars[0], TAILB);

  // ---- phase 1: SE pre-sum (old sesum_k) ----
  for (int u = blockIdx.x; u < 384; u += gridDim.x) {
    int bb = u >> 6, h = u & 63;
    int br = bb >> 1;
    int o = tid >> 2, wq = tid & 3;
    const float* gptr = (br == 0) ? g0 : ((br == 1) ? g1 : g2);
    const float* bptr = (br == 0) ? b0p : ((br == 1) ? b1p : b2p);
    float mu = bnacc_s[br * 64 + o] * (1.0f / POS);
    float var = bnacc_q[br * 64 + o] * (1.0f / POS) - mu * mu;
    float kk = gptr[o] / sqrtf(var + 1e-5f);
    float cc = bptr[o] - mu * kk;
    const float* row = yp + (size_t)bb * 262144 + (size_t)h * 4096 + o * 64 + wq * 16;
    float s = 0.0f;
#pragma unroll
    for (int j = 0; j < 4; ++j) {
      float4 v = *(const float4*)(row + j * 4);
      float a;
      a = v.x * kk + cc; s += (a > 0.0f) ? a : 0.0f;
      a = v.y * kk + cc; s += (a > 0.0f) ? a : 0.0f;
      a = v.z * kk + cc; s += (a > 0.0f) ? a : 0.0f;
      a = v.w * kk + cc; s += (a > 0.0f) ? a : 0.0f;
    }
    s += __shfl_down(s, 2, 4);
    s += __shfl_down(s, 1, 4);
    if (wq == 0) atomicAdd(&se_acc[bb * 64 + o], s);
  }
  gbar(&bars[1], TAILB);

  // ---- phase 2: SE MLP fold (blocks 0-5) + global-pool (block 6) ----
  if (blockIdx.x < 6) {
    int bb = blockIdx.x, br = bb >> 1;
    const float* w1 = (br == 0) ? w10 : ((br == 1) ? w11 : w12);
    const float* w2 = (br == 0) ? w20 : ((br == 1) ? w21 : w22);
    const float* gptr = (br == 0) ? g0 : ((br == 1) ? g1 : g2);
    const float* bptr = (br == 0) ? b0p : ((br == 1) ? b1p : b2p);
    if (tid < 64) sm[tid] = se_acc[bb * 64 + tid] * (1.0f / HW);
    __syncthreads();
    if (tid < 64) {
      int o = tid;
      float z[4];
#pragma unroll
      for (int j = 0; j < 4; ++j) {
        float s = 0.0f;
        for (int c2 = 0; c2 < 64; ++c2) s += sm[c2] * w1[j * 64 + c2];
        z[j] = (s > 0.0f) ? s : 0.0f;
      }
      float t = 0.0f;
#pragma unroll
      for (int j = 0; j < 4; ++j) t += z[j] * w2[o * 4 + j];
      t = sigmoidf_(t);
      float mu = bnacc_s[br * 64 + o] * (1.0f / POS);
      float var = bnacc_q[br * 64 + o] * (1.0f / POS) - mu * mu;
      float kk = gptr[o] / sqrtf(var + 1e-5f);
      float cc = bptr[o] - mu * kk;
      A1[bb * 64 + o] = kk * t;  // relu(x)*t == relu(x*t), t>0
      A0[bb * 64 + o] = cc * t;
    }
  } else if (blockIdx.x == 6) {
    int b = (tid >> 6) & 1, o = tid & 63;
    float gv = 0.0f, v = 0.0f, t = 0.0f;
    if (tid < 128) {
      gv = gb[o];
      for (int i = 0; i < 64; ++i) gv += xm[b * 64 + i] * gw[o * 64 + i];
      g0s[b][o] = gv;
    }
    __syncthreads();
    if (tid < 128) {
      float mu = 0.5f * (g0s[0][o] + g0s[1][o]);
      float df = g0s[0][o] - g0s[1][o];
      float var = 0.25f * df * df;
      v = (gv - mu) / sqrtf(var + 1e-5f) * bng[o] + bnb[o];
      v = (v > 0.0f) ? v : 0.0f;
      gp1s[b][o] = v;
    }
    __syncthreads();
    if (tid < 128) {
      float z[4];
#pragma unroll
      for (int j = 0; j < 4; ++j) {
        float s = 0.0f;
        for (int c2 = 0; c2 < 64; ++c2) s += gp1s[b][c2] * gpw1[j * 64 + c2];
        z[j] = (s > 0.0f) ? s : 0.0f;
      }
#pragma unroll
      for (int j = 0; j < 4; ++j) t += z[j] * gpw2[o * 4 + j];
      t = sigmoidf_(t);
      gpvs[b][o] = v * t;
    }
    __syncthreads();
    if (tid < 128) {
      float fg = 0.0f;
      for (int c2 = 0; c2 < 64; ++c2) fg += fuse_w[o * 256 + 192 + c2] * gpvs[b][c2];
      fgp[b * 64 + o] = fg;
    }
  }
  gbar(&bars[2], TAILB);

  // ---- phase 3: fuse GEMM + atomic fstat partials (old fuse_k) ----
  if (blockIdx.x < 256) {
    int bid = blockIdx.x;               // (b, h, w-half)
    int b = bid >> 7, h = (bid >> 1) & 63, wh = bid & 1;
    int wg = tid & 7, og = tid >> 3;    // 8 w-groups x 32 o-groups
    int w0 = wg * 4, o0 = og * 2;
    float acc[2][4] = {};
    for (int br = 0; br < 3; ++br) {
#pragma unroll
      for (int m = 0; m < 8; ++m) {     // stage As: 64 oc x 32 w
        int lin = tid + m * 256;
        int oc = lin >> 5, wl = lin & 31;
        float v = yp[(size_t)(br * 2 + b) * 262144 + (size_t)h * 4096 + oc * 64 + wh * 32 + wl];
        float a1 = A1[(br * 2 + b) * 64 + oc], a0 = A0[(br * 2 + b) * 64 + oc];
        v = v * a1 + a0;
        As[oc][wl] = (v > 0.0f) ? v : 0.0f;
      }
#pragma unroll
      for (int m = 0; m < 16; ++m) {    // stage Ws: 64 oc x 64 o
        int lin = tid + m * 256;
        int oc = lin >> 6, ol = lin & 63;
        Ws[oc][ol] = fwT[(br * 64 + oc) * 64 + ol];
      }
      __syncthreads();
#pragma unroll 8
      for (int ict = 0; ict < 64; ++ict) {
        float4 a = *reinterpret_cast<const float4*>(&As[ict][w0]);
        float2 wv = *reinterpret_cast<const float2*>(&Ws[ict][o0]);
        acc[0][0] += wv.x * a.x; acc[0][1] += wv.x * a.y; acc[0][2] += wv.x * a.z; acc[0][3] += wv.x * a.w;
        acc[1][0] += wv.y * a.x; acc[1][1] += wv.y * a.y; acc[1][2] += wv.y * a.z; acc[1][3] += wv.y * a.w;
      }
      __syncthreads();
    }
    float* tp = tmp + (size_t)(b * 64 + h) * 4096 + wh * 32;
    float ps[2], pq[2];
#pragma unroll
    for (int oo = 0; oo < 2; ++oo) {
      int o = o0 + oo;
      float bias = fb[o] + fgp[b * 64 + o];
      float4 v = make_float4(acc[oo][0] + bias, acc[oo][1] + bias,
                             acc[oo][2] + bias, acc[oo][3] + bias);
      *reinterpret_cast<float4*>(&tp[o * 64 + w0]) = v;
      ps[oo] = v.x + v.y + v.z + v.w;
      pq[oo] = v.x * v.x + v.y * v.y + v.z * v.z + v.w * v.w;
    }
    __syncthreads();
#pragma unroll
    for (int oo = 0; oo < 2; ++oo) { As[o0 + oo][wg] = ps[oo]; Ws[o0 + oo][wg] = pq[oo]; }
    __syncthreads();
    if (tid < 64) {
      float s = 0.0f, q = 0.0f;
#pragma unroll
      for (int r = 0; r < 8; ++r) { s += As[tid][r]; q += Ws[tid][r]; }
      atomicAdd(&fstat[tid], s);
      atomicAdd(&fstat[64 + tid], q);
    }
  }
  gbar(&bars[3], TAILB);

  // ---- phase 4: final BN+relu (old final_k) ----
  for (int u = blockIdx.x; u < 2048; u += gridDim.x) {
    int lin = u * 256 + tid;            // [0, 524288)
    int w = lin & 63, h2 = (lin >> 6) & 63, o = (lin >> 12) & 63, b = lin >> 18;
    float v = tmp[((size_t)(b * 64 + h2) * 64 + o) * 64 + w];
    float m = fstat[o] * (1.0f / POS);
    float var = fstat[64 + o] * (1.0f / POS) - m * m;
    float kk = fbn_g[o] / sqrtf(var + 1e-5f);
    float r = (v - m) * kk + fbn_b[o];
    out[lin] = (r > 0.0f) ? r : 0.0f;
  }
}

extern "C" void kernel_launch(void* const* d_in, const int* in_sizes, int n_in,
                              void* d_out, int out_size, void* d_ws, size_t ws_size,
                              hipStream_t stream) {
  const float* x = (const float*)d_in[0];
  const float* base_w[3]   = {(const float*)d_in[1],  (const float*)d_in[7],  (const float*)d_in[13]};
  const float* spline_w[3] = {(const float*)d_in[2],  (const float*)d_in[8],  (const float*)d_in[14]};
  const float* bn_g[3]     = {(const float*)d_in[3],  (const float*)d_in[9],  (const float*)d_in[15]};
  const float* bn_b[3]     = {(const float*)d_in[4],  (const float*)d_in[10], (const float*)d_in[16]};
  const float* se_w1[3]    = {(const float*)d_in[5],  (const float*)d_in[11], (const float*)d_in[17]};
  const float* se_w2[3]    = {(const float*)d_in[6],  (const float*)d_in[12], (const float*)d_in[18]};
  const float* gp_conv_w = (const float*)d_in[19];
  const float* gp_conv_b = (const float*)d_in[20];
  const float* gp_bn_g   = (const float*)d_in[21];
  const float* gp_bn_b   = (const float*)d_in[22];
  const float* gp_se_w1  = (const float*)d_in[23];
  const float* gp_se_w2  = (const float*)d_in[24];
  const float* fuse_w    = (const float*)d_in[25];
  const float* fuse_b    = (const float*)d_in[26];
  const float* fuse_bn_g = (const float*)d_in[27];
  const float* fuse_bn_b = (const float*)d_in[28];
  float* out = (float*)d_out;

  char* wsp = (char*)d_ws;
  auto alloc = [&](size_t bytes) -> char* {
    char* p = wsp;
    wsp += (bytes + 255) & ~(size_t)255;
    return p;
  };
  __hip_bfloat16* F0 = (__hip_bfloat16*)alloc((size_t)2 * 64 * 76 * 448 * 2);
  __hip_bfloat16* F1 = (__hip_bfloat16*)alloc((size_t)2 * 64 * 88 * 640 * 2);
  __hip_bfloat16* F2 = (__hip_bfloat16*)alloc((size_t)2 * 64 * 100 * 832 * 2);
  __hip_bfloat16* W0 = (__hip_bfloat16*)alloc((size_t)9 * 64 * 448 * 2);
  __hip_bfloat16* W1 = (__hip_bfloat16*)alloc((size_t)9 * 64 * 640 * 2);
  __hip_bfloat16* W2 = (__hip_bfloat16*)alloc((size_t)9 * 64 * 832 * 2);
  float* C0r   = (float*)alloc((size_t)3 * 3 * 64 * 4);
  float* ypart = (float*)alloc((size_t)3 * SLAB * 4);   // 3 ki-slabs; slab0 -> y
  float* yp    = ypart;
  float* tmp   = ypart + SLAB;   // slab1 dead after tail phase 0 -> reuse
  float* A1  = (float*)alloc(384 * 4);
  float* A0  = (float*)alloc(384 * 4);
  float* xm  = (float*)alloc(128 * 4);
  float* fgp = (float*)alloc(128 * 4);
  float* fwT = (float*)alloc((size_t)12288 * 4);
  float* accz = (float*)alloc(1024 * 4);  // fstat[128]|bnacc_s[192]|bnacc_q[192]|se_acc[384]|bars
  float* fstat   = accz;
  float* bnacc_s = accz + 128;
  float* bnacc_q = accz + 320;
  float* se_acc  = accz + 512;
  int*   bars    = (int*)(accz + 896);   // 4 barrier counters, zeroed by prepfeat

  prepfeat_k<<<6752, 256, 0, stream>>>(x, F0, F1, F2,
                                       base_w[0], spline_w[0], base_w[1], spline_w[1],
                                       base_w[2], spline_w[2], W0, W1, W2, C0r,
                                       fuse_w, fwT, xm, accz);
  conv_all_k<<<576, 384, 0, stream>>>(
      (const short*)F0, (const short*)F1, (const short*)F2,
      (const short*)W0, (const short*)W1, (const short*)W2, C0r, ypart);
  tail_k<<<TAILB, 256, 0, stream>>>(
      yp, bnacc_s, bnacc_q,
      bn_g[0], bn_b[0], bn_g[1], bn_b[1], bn_g[2], bn_b[2],
      se_w1[0], se_w1[1], se_w1[2], se_w2[0], se_w2[1], se_w2[2],
      A1, A0, xm, gp_conv_w, gp_conv_b, gp_bn_g, gp_bn_b,
      gp_se_w1, gp_se_w2, fuse_w, fgp, fwT, fuse_b,
      tmp, fstat, se_acc, bars, fuse_bn_g, fuse_bn_b, out);
}

// Round 17
// 246.937 us; speedup vs baseline: 1.6891x; 1.6891x over previous
//
#include <hip/hip_runtime.h>
#include <hip/hip_bf16.h>
#include <math.h>

#define DEV __device__ __forceinline__

static constexpr int HW  = 4096;    // H*W
static constexpr int POS = 8192;    // B*H*W
static constexpr int SLAB = 6 * 64 * 4096;  // one ki-slab (floats)

typedef __attribute__((ext_vector_type(8)))  short short8;
typedef __attribute__((ext_vector_type(16))) float floatx16;
typedef __attribute__((ext_vector_type(4)))  unsigned int uint4v;

// ---------- B-spline basis (order 3); constant denominators -> mul by recip ----------
template<int G>
DEV void bsplines(float x, float* out /* G+3 values */) {
  const float h = 2.0f / (float)G;
  float knot[G + 7];
#pragma unroll
  for (int t = 0; t < G + 7; ++t) knot[t] = -1.0f + (float)(t - 3) * h;
  float bb[G + 6];
#pragma unroll
  for (int t = 0; t < G + 6; ++t) bb[t] = (x >= knot[t] && x < knot[t + 1]) ? 1.0f : 0.0f;
#pragma unroll
  for (int j = 1; j <= 3; ++j) {
    const float inv = (float)G / (2.0f * (float)j);   // 1/(j*h), compile-time
#pragma unroll
    for (int t = 0; t < G + 6 - j; ++t) {
      float left  = (x - knot[t]) * inv;
      float right = (knot[t + j + 1] - x) * inv;
      bb[t] = left * bb[t] + right * bb[t + 1];
    }
  }
#pragma unroll
  for (int t = 0; t < G + 3; ++t) out[t] = bb[t];
}

DEV float sigmoidf_(float x) { return 1.0f / (1.0f + __expf(-x)); }

DEV float block_reduce_256(float v, float* sb) {  // blockDim.x == 256
  __syncthreads();
#pragma unroll
  for (int off = 32; off > 0; off >>= 1) v += __shfl_down(v, off, 64);
  int lane = threadIdx.x & 63, wid = threadIdx.x >> 6;
  if (lane == 0) sb[wid] = v;
  __syncthreads();
  return sb[0] + sb[1] + sb[2] + sb[3];
}

// ================= prep bodies =================
// Fragment-major layouts (R5, proven):
//   W'[tap][s][half][lane*8]   (per tap: s<KC/16, 1024 elem per s)
//   F'[b][hs][s][wp][16]       (per row: s-major, 16 k per wp)
// R15 post-mortem: SW grid barriers cost ~48us each regardless of poll type
// (platform property) -> fusion abandoned; back to proven 6-kernel pipeline.
// wprep vectorized (R16): 8 consecutive ic share one fragment-major short8
// dst -> 8 elems/thread, 1 vector store; 4320 -> 540 blocks.

template<int CF>
DEV void wprep_body(const float* __restrict__ base_w, const float* __restrict__ spline_w,
                    __hip_bfloat16* __restrict__ Wt, int bid) {
  constexpr int KC = 64 * CF;        // KC % 8 == 0 for all branches
  int lin = (bid * 256 + threadIdx.x) * 8;  // (tap, o, ic) base; 8 elems/thread
  int ic = lin % KC;
  int rest = lin / KC;               // 8 consecutive ic stay in one (tap,o)
  int o = rest & 63, tap = rest >> 6;
  short8 vout;
#pragma unroll
  for (int e = 0; e < 8; ++e) {
    int ice = ic + e;
    int c = ice % CF, i = ice / CF;
    float v = (c == 0) ? base_w[(o * 64 + i) * 9 + tap]
                       : spline_w[((o * 64 + i) * 9 + tap) * (CF - 1) + (c - 1)];
    __hip_bfloat16 bv = __float2bfloat16(v);
    vout[e] = *reinterpret_cast<short*>(&bv);
  }
  // dst: s=ic>>4, q=(ic&15)>>3 const across the 8; r=0..7 consecutive
  int s = ic >> 4, q = (ic & 15) >> 3, hh = o >> 5;
  int l = q * 32 + (o & 31);
  *(short8*)(Wt + (size_t)tap * (64 * KC) + s * 1024 + hh * 512 + l * 8) = vout;
}

template<int G>
DEV void c0r_body(int ki, const float* __restrict__ sw, float* __restrict__ out,
                  float* shmem /* >=256 floats */) {
  constexpr int NB = G + 3;
  int o = threadIdx.x & 63, part = threadIdx.x >> 6;  // 4 parts over i
  float b0[NB];
  bsplines<G>(0.0f, b0);
  float s = 0.0f;
  for (int kj = 0; kj < 3; ++kj) {
    int tap = ki * 3 + kj;
    for (int i = part * 16; i < part * 16 + 16; ++i) {
      const float* p = sw + ((size_t)(o * 64 + i) * 9 + tap) * NB;
#pragma unroll
      for (int c = 0; c < NB; ++c) s += p[c] * b0[c];
    }
  }
  shmem[part * 64 + o] = s;
  __syncthreads();
  if (part == 0)
    out[ki * 64 + o] = shmem[o] + shmem[64 + o] + shmem[128 + o] + shmem[192 + o];
}

// ---- merged interior features: one x load feeds all 3 branches ----
template<int G, int RB>
DEV void feat_stage(float xv, float s, __hip_bfloat16* lds, int ws, int i) {
  constexpr int CF = G + 4;
  constexpr int RS = 64 * CF + 16;    // padded region stride (bf16)
  float bas[G + 3];
  bsplines<G>(xv, bas);
  __hip_bfloat16* d = lds + RB + ws * RS + i * CF;
  d[0] = __float2bfloat16(s);
#pragma unroll
  for (int c = 1; c < CF; ++c) d[c] = __float2bfloat16(bas[c - 1]);
}

template<int CF, int D, int RBu>
DEV void feat_copy(__hip_bfloat16* __restrict__ F, int b, int h, int wg, const uint4v* l) {
  constexpr int WP = 64 + 2 * D;
  constexpr int KC = 64 * CF;
  uint4v* g = (uint4v*)(F + (size_t)(b * 64 + h) * WP * KC);
  for (int t = threadIdx.x; t < 32 * CF; t += 256) {
    int sc = t >> 3, r = t & 7, wl = r >> 1, k4 = r & 1;
    g[(size_t)(sc * WP + D + wg * 4 + wl) * 2 + k4] = l[RBu + wl * (8 * CF + 2) + sc * 2 + k4];
  }
}

DEV void feat_interior(const float* __restrict__ x, __hip_bfloat16* F0, __hip_bfloat16* F1,
                       __hip_bfloat16* F2, int bid, __hip_bfloat16* lds) {
  int tid = threadIdx.x;
  int ws = tid & 3, i = tid >> 2;
  int wg = bid & 15, h = (bid >> 4) & 63, b = bid >> 10;
  int w = wg * 4 + ws;
  float xv = x[((size_t)(b * 64 + i) * 64 + h) * 64 + w];   // always in-bounds
  float s = xv * sigmoidf_(xv);
  feat_stage<3, 0>(xv, s, lds, ws, i);      // CF=7,  RS=464
  feat_stage<6, 1856>(xv, s, lds, ws, i);   // CF=10, RS=656
  feat_stage<9, 4480>(xv, s, lds, ws, i);   // CF=13, RS=848
  __syncthreads();
  const uint4v* l = (const uint4v*)lds;
  feat_copy<7, 6, 0>(F0, b, h, wg, l);
  feat_copy<10, 12, 232>(F1, b, h, wg, l);
  feat_copy<13, 18, 560>(F2, b, h, wg, l);
}

// ---- constant halo fill: features of x=0 at wp in [0,D) u [64+D,WP) ----
template<int G, int D>
DEV void halo_body(__hip_bfloat16* __restrict__ F, int bidl, __hip_bfloat16* ldsb) {
  constexpr int CF = G + 4;
  constexpr int WP = 64 + 2 * D;
  constexpr int KC = 64 * CF;
  constexpr int PW = 8 * CF;      // uint4 per (row, halo-wp)
  constexpr int D2 = 2 * D;
  int tid = threadIdx.x;
  float bas0[G + 3];
  bsplines<G>(0.0f, bas0);        // bitwise-identical to interior xv=0 path
  for (int k = tid; k < KC; k += 256) {
    int c = k % CF;
    float v = 0.0f;               // c==0: silu(0)=0
#pragma unroll
    for (int cc = 1; cc < CF; ++cc) v = (c == cc) ? bas0[cc - 1] : v;
    ldsb[k] = __float2bfloat16(v);
  }
  __syncthreads();
  const uint4v* l = (const uint4v*)ldsb;
  uint4v* g = (uint4v*)F;
#pragma unroll
  for (int u = 0; u < 16; ++u) {
    int t = bidl * 4096 + u * 256 + tid;
    int rw = t / PW, r2 = t - rw * PW;
    int sc = r2 >> 1, k4 = r2 & 1;
    int row = rw / D2, wj = rw - row * D2;
    int wp = (wj < D) ? wj : 64 + wj;
    g[(size_t)row * (WP * KC / 8) + (size_t)(sc * WP + wp) * 2 + k4] = l[sc * 2 + k4];
  }
}

// ========== merged prep + features (data-independent, disjoint bid ranges) ==========
__global__ void prepfeat_k(const float* __restrict__ x,
                           __hip_bfloat16* F0, __hip_bfloat16* F1, __hip_bfloat16* F2,
                           const float* bw0, const float* sw0, const float* bw1,
                           const float* sw1, const float* bw2, const float* sw2,
                           __hip_bfloat16* W0, __hip_bfloat16* W1, __hip_bfloat16* W2,
                           float* C0r, const float* fuse_w, float* fwT,
                           float* xm, float* accz /* 896 floats */) {
  __shared__ uint4v ldsq[984];                  // 3 regions: 4*(464+656+848) bf16 = 15744B
  __shared__ float shmem[256];                  // prep reductions
  __hip_bfloat16* lds = (__hip_bfloat16*)ldsq;
  int bid = blockIdx.x, tid = threadIdx.x;
  if (bid < 2048)      { feat_interior(x, F0, F1, F2, bid, lds); return; }
  else if (bid < 2069) { halo_body<3, 6>(F0, bid - 2048, lds); return; }   // 21 blocks
  else if (bid < 2129) { halo_body<6, 12>(F1, bid - 2069, lds); return; }  // 60 blocks
  else if (bid < 2246) { halo_body<9, 18>(F2, bid - 2129, lds); return; }  // 117 blocks
  int pb = bid - 2246;                          // [0, 726) prep blocks
  if (pb < 126)       { wprep_body<7>(bw0, sw0, W0, pb); }
  else if (pb < 306)  { wprep_body<10>(bw1, sw1, W1, pb - 126); }
  else if (pb < 540)  { wprep_body<13>(bw2, sw2, W2, pb - 306); }
  else if (pb < 549) {
    int idx = pb - 540, br = idx / 3, ki = idx % 3;
    if (br == 0)      c0r_body<3>(ki, sw0, C0r, shmem);
    else if (br == 1) c0r_body<6>(ki, sw1, C0r + 192, shmem);
    else              c0r_body<9>(ki, sw2, C0r + 384, shmem);
  } else if (pb < 597) {  // fuse_w transpose (branch part)
    int lin = (pb - 549) * 256 + tid;  // [0, 12288)
    int o = lin & 63, i2 = lin >> 6;
    fwT[i2 * 64 + o] = fuse_w[o * 256 + i2];
  } else if (pb < 725) {  // x mean per (b,i)
    int bi = pb - 597;
    const float* p = x + (size_t)bi * HW;
    float s = 0.0f;
    for (int t = tid; t < HW; t += 256) s += p[t];
    s = block_reduce_256(s, shmem);
    if (tid == 0) xm[bi] = s * (1.0f / HW);
  } else {  // zero accumulators: fstat[128] | bnacc_s[192] | bnacc_q[192] | se_acc[384]
    for (int t = tid; t < 896; t += 256) accz[t] = 0.0f;
  }
}

// ============ KAN conv: R7 ki-centric (proven 44us) — byte-identical ============
DEV floatx16 mfma_bf16(short8 a, short8 b, floatx16 c) {
  return __builtin_amdgcn_mfma_f32_32x32x16_bf16(a, b, c, 0, 0, 0);
}

template<int CF, int DD>
DEV void conv_dev(int ki, int b, int hp, const short* __restrict__ F,
                  const short* __restrict__ W, const float* __restrict__ C0r,
                  float* __restrict__ ypart, int br, float* __restrict__ red) {
  constexpr int KC = 64 * CF;
  constexpr int WP = 64 + 2 * DD;
  int wid = threadIdx.x >> 6;       // 0..5
  int wv  = wid & 1;                // source-row select
  int kjw = wid >> 1;               // kj tap owned by this wave
  int lane = threadIdx.x & 63;
  int lr = lane & 31, lq = lane >> 5;
  int hs = hp * 2 + wv;             // source row (always valid)
  int h_out = hs - (ki - 1) * DD;   // output row this source feeds for this ki
  bool valid = (h_out >= 0 && h_out < 64);
  int h_tgt = valid ? h_out : (h_out < 0 ? h_out + 64 : h_out - 64);  // mirror: C0 rows
  float* yb = ypart + (size_t)ki * SLAB + ((size_t)((br * 2 + b) * 64 + h_tgt)) * 4096;

  floatx16 acc[2][2];
#pragma unroll
  for (int ot = 0; ot < 2; ++ot)
#pragma unroll
    for (int wh = 0; wh < 2; ++wh)
#pragma unroll
      for (int r = 0; r < 16; ++r) acc[ot][wh][r] = 0.0f;

  if (valid) {
    // fragment-major bases: every load is base + s*const + lane-contiguous 16B
    const short* wl_ = W + (size_t)(ki * 3 + kjw) * (64 * KC) + lane * 8;
    const short* fB  = F + (size_t)(b * 64 + hs) * WP * KC
                         + (kjw * DD + lr) * 16 + lq * 8;
#pragma unroll 4
    for (int s = 0; s < 4 * CF; ++s) {   // 16-K per step
      short8 a0 = *(const short8*)(wl_ + s * 1024);
      short8 a1 = *(const short8*)(wl_ + s * 1024 + 512);
      short8 b0 = *(const short8*)(fB + s * (WP * 16));
      short8 b1 = *(const short8*)(fB + s * (WP * 16) + 512);
      acc[0][0] = mfma_bf16(a0, b0, acc[0][0]);
      acc[0][1] = mfma_bf16(a0, b1, acc[0][1]);
      acc[1][0] = mfma_bf16(a1, b0, acc[1][0]);
      acc[1][1] = mfma_bf16(a1, b1, acc[1][1]);
    }
  }

  // ---- reduce the 3 kj partials through LDS (stride 65: conflict-free) ----
  float* slot = red + (size_t)wv * (64 * 65) + lane * 65;
  if (kjw == 2 && valid) {
#pragma unroll
    for (int ot = 0; ot < 2; ++ot)
#pragma unroll
      for (int wh = 0; wh < 2; ++wh)
#pragma unroll
        for (int r = 0; r < 16; ++r) slot[(ot * 2 + wh) * 16 + r] = acc[ot][wh][r];
  }
  __syncthreads();
  if (kjw == 1 && valid) {
#pragma unroll
    for (int ot = 0; ot < 2; ++ot)
#pragma unroll
      for (int wh = 0; wh < 2; ++wh)
#pragma unroll
        for (int r = 0; r < 16; ++r) {
          int idx = (ot * 2 + wh) * 16 + r;
          slot[idx] += acc[ot][wh][r];
        }
  }
  __syncthreads();
  if (kjw != 0) return;

  if (!valid) {  // paired output row's source is OOB: constant C0 contribution
    const float* c0 = C0r + (br * 3 + ki) * 64;
#pragma unroll
    for (int wh = 0; wh < 2; ++wh) {
      int w = wh * 32 + lr;
#pragma unroll
      for (int ot = 0; ot < 2; ++ot)
#pragma unroll
        for (int r = 0; r < 16; ++r) {
          int o = (r & 3) + 8 * (r >> 2) + 4 * lq + 32 * ot;
          yb[(size_t)o * 64 + w] = c0[o];
        }
    }
    return;
  }

#pragma unroll
  for (int ot = 0; ot < 2; ++ot)
#pragma unroll
    for (int wh = 0; wh < 2; ++wh) {
      int w = wh * 32 + lr;
#pragma unroll
      for (int r = 0; r < 16; ++r) {
        int o = (r & 3) + 8 * (r >> 2) + 4 * lq + 32 * ot;
        yb[(size_t)o * 64 + w] = acc[ot][wh][r] + slot[(ot * 2 + wh) * 16 + r];
      }
    }
}

__global__ __launch_bounds__(384) void conv_all_k(
    const short* __restrict__ F0, const short* __restrict__ F1, const short* __restrict__ F2,
    const short* __restrict__ W0, const short* __restrict__ W1, const short* __restrict__ W2,
    const float* __restrict__ C0r, float* __restrict__ ypart) {
  __shared__ float red[2 * 64 * 65];    // 33.3 KB partial-acc reduction buffer
  // XCD swizzle: ki-siblings at bid, bid+8, bid+16 -> same XCD (bid % 8 fixed)
  int bid = blockIdx.x;                 // [0,576)
  int e  = bid & 7;
  int t  = bid >> 3;                    // [0,72)
  int ki = t % 3;
  int m  = (t / 3) * 8 + e;             // [0,192) combo (br,b,hp)
  int br = m >> 6, b = (m >> 5) & 1, hp = m & 31;
  if (br == 0)      conv_dev<7, 6>(ki, b, hp, F0, W0, C0r, ypart, 0, red);
  else if (br == 1) conv_dev<10, 12>(ki, b, hp, F1, W1, C0r, ypart, 1, red);
  else              conv_dev<13, 18>(ki, b, hp, F2, W2, C0r, ypart, 2, red);
}

// ====== reduce 3 ki-slabs into slab0 + atomic per-(br,o) BN partials ======
__global__ void rb_k(float* __restrict__ yp, float* __restrict__ bnacc_s,
                     float* __restrict__ bnacc_q) {
  int bid = blockIdx.x;                 // [0,1536) = bb(6) x chunk(256)
  int bb = bid / 256, chunk = bid % 256;
  int br = bb >> 1;
  int tid = threadIdx.x;
  size_t base = (size_t)bb * 262144 + chunk * 1024 + tid * 4;
  float4 v = *(const float4*)(yp + base);
#pragma unroll
  for (int s2 = 1; s2 < 3; ++s2) {
    float4 u = *(const float4*)(yp + base + (size_t)s2 * SLAB);
    v.x += u.x; v.y += u.y; v.z += u.z; v.w += u.w;
  }
  *(float4*)(yp + base) = v;
  float s = v.x + v.y + v.z + v.w;
  float q = v.x * v.x + v.y * v.y + v.z * v.z + v.w * v.w;
  s += __shfl_down(s, 8, 16); s += __shfl_down(s, 4, 16);
  s += __shfl_down(s, 2, 16); s += __shfl_down(s, 1, 16);
  q += __shfl_down(q, 8, 16); q += __shfl_down(q, 4, 16);
  q += __shfl_down(q, 2, 16); q += __shfl_down(q, 1, 16);
  if ((tid & 15) == 0) {
    int o = (chunk * 16 + (tid >> 4)) & 63;
    atomicAdd(&bnacc_s[br * 64 + o], s);
    atomicAdd(&bnacc_q[br * 64 + o], q);
  }
}

// ====== SE pre-sum: atomic sum over (h,w) of relu(bn(y)) per (bb,o) ======
__global__ void sesum_k(const float* __restrict__ y, const float* __restrict__ bnacc_s,
                        const float* __restrict__ bnacc_q,
                        const float* g0, const float* b0p, const float* g1, const float* b1p,
                        const float* g2, const float* b2p, float* __restrict__ se_acc) {
  int bid = blockIdx.x;                 // [0,384) = bb(6) x h(64)
  int bb = bid >> 6, h = bid & 63;
  int br = bb >> 1;
  int tid = threadIdx.x;
  int o = tid >> 2, wq = tid & 3;
  const float* gptr = (br == 0) ? g0 : ((br == 1) ? g1 : g2);
  const float* bptr = (br == 0) ? b0p : ((br == 1) ? b1p : b2p);
  float mu = bnacc_s[br * 64 + o] * (1.0f / POS);
  float var = bnacc_q[br * 64 + o] * (1.0f / POS) - mu * mu;
  float kk = gptr[o] / sqrtf(var + 1e-5f);
  float cc = bptr[o] - mu * kk;
  const float* row = y + (size_t)bb * 262144 + (size_t)h * 4096 + o * 64 + wq * 16;
  float s = 0.0f;
#pragma unroll
  for (int j = 0; j < 4; ++j) {
    float4 v = *(const float4*)(row + j * 4);
    float a;
    a = v.x * kk + cc; s += (a > 0.0f) ? a : 0.0f;
    a = v.y * kk + cc; s += (a > 0.0f) ? a : 0.0f;
    a = v.z * kk + cc; s += (a > 0.0f) ? a : 0.0f;
    a = v.w * kk + cc; s += (a > 0.0f) ? a : 0.0f;
  }
  s += __shfl_down(s, 2, 4);
  s += __shfl_down(s, 1, 4);
  if (wq == 0) atomicAdd(&se_acc[bb * 64 + o], s);
}

// ============ fuse GEMM + integrated SE-MLP/GP prologue (semlp_gp_k folded in) ============
__global__ __launch_bounds__(256) void fuse_k(
    const float* __restrict__ y, const float* __restrict__ fwT, const float* __restrict__ fb,
    const float* __restrict__ se_acc, const float* __restrict__ bnacc_s,
    const float* __restrict__ bnacc_q,
    const float* g0, const float* b0p, const float* g1, const float* b1p,
    const float* g2, const float* b2p,
    const float* w10, const float* w11, const float* w12,
    const float* w20, const float* w21, const float* w22,
    const float* __restrict__ xm, const float* gw, const float* gb,
    const float* bng, const float* bnb, const float* gpw1, const float* gpw2,
    const float* __restrict__ fuse_w,
    float* __restrict__ tmp, float* __restrict__ fstat) {
  int bid = blockIdx.x;                 // [0,256): (b, h, w-half)
  int b = bid >> 7, h = (bid >> 1) & 63, wh = bid & 1;
  int tid = threadIdx.x;
  __shared__ float As[64][32];
  __shared__ float Ws[64][64];
  __shared__ float A1s[3][64], A0s[3][64], fgps[64];
  __shared__ float pro[3][64], gp1v[64], gpv2[64];

  // ---- prologue: 4 groups of 64 threads; ~20K MACs (old semlp_gp_k, folded) ----
  int grp = tid >> 6, po = tid & 63;
  float gv = 0.0f, gv_other = 0.0f;
  if (grp < 3) {
    pro[grp][po] = se_acc[(grp * 2 + b) * 64 + po] * (1.0f / HW);
  } else {  // gp: compute gv for BOTH b (BN over batch needs both)
    float g_[2];
#pragma unroll
    for (int b2 = 0; b2 < 2; ++b2) {
      float s = gb[po];
      for (int i = 0; i < 64; ++i) s += xm[b2 * 64 + i] * gw[po * 64 + i];
      g_[b2] = s;
    }
    gv = g_[b]; gv_other = g_[1 - b];
  }
  __syncthreads();
  float v_gp = 0.0f;
  if (grp < 3) {
    const float* w1 = (grp == 0) ? w10 : ((grp == 1) ? w11 : w12);
    const float* w2 = (grp == 0) ? w20 : ((grp == 1) ? w21 : w22);
    const float* gptr = (grp == 0) ? g0 : ((grp == 1) ? g1 : g2);
    const float* bptr = (grp == 0) ? b0p : ((grp == 1) ? b1p : b2p);
    float z[4];
#pragma unroll
    for (int j = 0; j < 4; ++j) {
      float s = 0.0f;
      for (int c2 = 0; c2 < 64; ++c2) s += pro[grp][c2] * w1[j * 64 + c2];
      z[j] = (s > 0.0f) ? s : 0.0f;
    }
    float t = 0.0f;
#pragma unroll
    for (int j = 0; j < 4; ++j) t += z[j] * w2[po * 4 + j];
    t = sigmoidf_(t);
    float mu = bnacc_s[grp * 64 + po] * (1.0f / POS);
    float var = bnacc_q[grp * 64 + po] * (1.0f / POS) - mu * mu;
    float kk = gptr[po] / sqrtf(var + 1e-5f);
    float cc = bptr[po] - mu * kk;
    A1s[grp][po] = kk * t;   // relu(x)*t == relu(x*t), t>0
    A0s[grp][po] = cc * t;
  } else {
    float mu = 0.5f * (gv + gv_other);
    float df = gv - gv_other;
    float var = 0.25f * df * df;
    v_gp = (gv - mu) / sqrtf(var + 1e-5f) * bng[po] + bnb[po];
    v_gp = (v_gp > 0.0f) ? v_gp : 0.0f;
    gp1v[po] = v_gp;
  }
  __syncthreads();
  if (grp == 3) {
    float z[4];
#pragma unroll
    for (int j = 0; j < 4; ++j) {
      float s = 0.0f;
      for (int c2 = 0; c2 < 64; ++c2) s += gp1v[c2] * gpw1[j * 64 + c2];
      z[j] = (s > 0.0f) ? s : 0.0f;
    }
    float t = 0.0f;
#pragma unroll
    for (int j = 0; j < 4; ++j) t += z[j] * gpw2[po * 4 + j];
    gpv2[po] = v_gp * sigmoidf_(t);
  }
  __syncthreads();
  if (grp == 3) {
    float fg = 0.0f;
    for (int c2 = 0; c2 < 64; ++c2) fg += fuse_w[po * 256 + 192 + c2] * gpv2[c2];
    fgps[po] = fg;
  }
  // fgps first read is in the epilogue, after >=2 __syncthreads below -> visible.

  // ---- main fuse GEMM (unchanged; A1/A0/fgp now from LDS) ----
  int wg = tid & 7, og = tid >> 3;      // 8 w-groups x 32 o-groups
  int w0 = wg * 4, o0 = og * 2;
  float acc[2][4] = {};
  for (int br = 0; br < 3; ++br) {
#pragma unroll
    for (int m = 0; m < 8; ++m) {       // stage As: 64 oc x 32 w
      int lin = tid + m * 256;
      int oc = lin >> 5, wl = lin & 31;
      float v = y[(size_t)(br * 2 + b) * 262144 + (size_t)h * 4096 + oc * 64 + wh * 32 + wl];
      v = v * A1s[br][oc] + A0s[br][oc];
      As[oc][wl] = (v > 0.0f) ? v : 0.0f;
    }
#pragma unroll
    for (int m = 0; m < 16; ++m) {      // stage Ws: 64 oc x 64 o
      int lin = tid + m * 256;
      int oc = lin >> 6, ol = lin & 63;
      Ws[oc][ol] = fwT[(br * 64 + oc) * 64 + ol];
    }
    __syncthreads();
#pragma unroll 8
    for (int ict = 0; ict < 64; ++ict) {
      float4 a = *reinterpret_cast<const float4*>(&As[ict][w0]);
      float2 wv = *reinterpret_cast<const float2*>(&Ws[ict][o0]);
      acc[0][0] += wv.x * a.x; acc[0][1] += wv.x * a.y; acc[0][2] += wv.x * a.z; acc[0][3] += wv.x * a.w;
      acc[1][0] += wv.y * a.x; acc[1][1] += wv.y * a.y; acc[1][2] += wv.y * a.z; acc[1][3] += wv.y * a.w;
    }
    __syncthreads();
  }
  float* tp = tmp + (size_t)(b * 64 + h) * 4096 + wh * 32;
  float ps[2], pq[2];
#pragma unroll
  for (int oo = 0; oo < 2; ++oo) {
    int o = o0 + oo;
    float bias = fb[o] + fgps[o];
    float4 v = make_float4(acc[oo][0] + bias, acc[oo][1] + bias,
                           acc[oo][2] + bias, acc[oo][3] + bias);
    *reinterpret_cast<float4*>(&tp[o * 64 + w0]) = v;
    ps[oo] = v.x + v.y + v.z + v.w;
    pq[oo] = v.x * v.x + v.y * v.y + v.z * v.z + v.w * v.w;
  }
  __syncthreads();
#pragma unroll
  for (int oo = 0; oo < 2; ++oo) { As[o0 + oo][wg] = ps[oo]; Ws[o0 + oo][wg] = pq[oo]; }
  __syncthreads();
  if (tid < 64) {
    float s = 0.0f, q = 0.0f;
#pragma unroll
    for (int r = 0; r < 8; ++r) { s += As[tid][r]; q += Ws[tid][r]; }
    atomicAdd(&fstat[tid], s);
    atomicAdd(&fstat[64 + tid], q);
  }
}

// ---------- final BN+relu, write (B,Co,H,W) ----------
__global__ void final_k(const float* __restrict__ tmp, const float* __restrict__ fstat,
                        const float* __restrict__ g, const float* __restrict__ bb,
                        float* __restrict__ out) {
  int lin = blockIdx.x * 256 + threadIdx.x;  // [0, 524288)
  int w = lin & 63, h2 = (lin >> 6) & 63, o = (lin >> 12) & 63, b = lin >> 18;
  float v = tmp[((size_t)(b * 64 + h2) * 64 + o) * 64 + w];
  float m = fstat[o] * (1.0f / POS);
  float var = fstat[64 + o] * (1.0f / POS) - m * m;
  float kk = g[o] / sqrtf(var + 1e-5f);
  float r = (v - m) * kk + bb[o];
  out[lin] = (r > 0.0f) ? r : 0.0f;
}

extern "C" void kernel_launch(void* const* d_in, const int* in_sizes, int n_in,
                              void* d_out, int out_size, void* d_ws, size_t ws_size,
                              hipStream_t stream) {
  const float* x = (const float*)d_in[0];
  const float* base_w[3]   = {(const float*)d_in[1],  (const float*)d_in[7],  (const float*)d_in[13]};
  const float* spline_w[3] = {(const float*)d_in[2],  (const float*)d_in[8],  (const float*)d_in[14]};
  const float* bn_g[3]     = {(const float*)d_in[3],  (const float*)d_in[9],  (const float*)d_in[15]};
  const float* bn_b[3]     = {(const float*)d_in[4],  (const float*)d_in[10], (const float*)d_in[16]};
  const float* se_w1[3]    = {(const float*)d_in[5],  (const float*)d_in[11], (const float*)d_in[17]};
  const float* se_w2[3]    = {(const float*)d_in[6],  (const float*)d_in[12], (const float*)d_in[18]};
  const float* gp_conv_w = (const float*)d_in[19];
  const float* gp_conv_b = (const float*)d_in[20];
  const float* gp_bn_g   = (const float*)d_in[21];
  const float* gp_bn_b   = (const float*)d_in[22];
  const float* gp_se_w1  = (const float*)d_in[23];
  const float* gp_se_w2  = (const float*)d_in[24];
  const float* fuse_w    = (const float*)d_in[25];
  const float* fuse_b    = (const float*)d_in[26];
  const float* fuse_bn_g = (const float*)d_in[27];
  const float* fuse_bn_b = (const float*)d_in[28];
  float* out = (float*)d_out;

  char* wsp = (char*)d_ws;
  auto alloc = [&](size_t bytes) -> char* {
    char* p = wsp;
    wsp += (bytes + 255) & ~(size_t)255;
    return p;
  };
  __hip_bfloat16* F0 = (__hip_bfloat16*)alloc((size_t)2 * 64 * 76 * 448 * 2);
  __hip_bfloat16* F1 = (__hip_bfloat16*)alloc((size_t)2 * 64 * 88 * 640 * 2);
  __hip_bfloat16* F2 = (__hip_bfloat16*)alloc((size_t)2 * 64 * 100 * 832 * 2);
  __hip_bfloat16* W0 = (__hip_bfloat16*)alloc((size_t)9 * 64 * 448 * 2);
  __hip_bfloat16* W1 = (__hip_bfloat16*)alloc((size_t)9 * 64 * 640 * 2);
  __hip_bfloat16* W2 = (__hip_bfloat16*)alloc((size_t)9 * 64 * 832 * 2);
  float* C0r   = (float*)alloc((size_t)3 * 3 * 64 * 4);
  float* ypart = (float*)alloc((size_t)3 * SLAB * 4);   // 3 ki-slabs; slab0 -> y
  float* y     = ypart;
  float* tmp   = ypart + SLAB;   // slab1 dead after rb_k -> reuse
  float* xm  = (float*)alloc(128 * 4);
  float* fwT = (float*)alloc((size_t)12288 * 4);
  float* accz = (float*)alloc(896 * 4);  // fstat[128] | bnacc_s[192] | bnacc_q[192] | se_acc[384]
  float* fstat   = accz;
  float* bnacc_s = accz + 128;
  float* bnacc_q = accz + 320;
  float* se_acc  = accz + 512;

  prepfeat_k<<<2972, 256, 0, stream>>>(x, F0, F1, F2,
                                       base_w[0], spline_w[0], base_w[1], spline_w[1],
                                       base_w[2], spline_w[2], W0, W1, W2, C0r,
                                       fuse_w, fwT, xm, accz);
  conv_all_k<<<576, 384, 0, stream>>>(
      (const short*)F0, (const short*)F1, (const short*)F2,
      (const short*)W0, (const short*)W1, (const short*)W2, C0r, ypart);
  rb_k<<<1536, 256, 0, stream>>>(ypart, bnacc_s, bnacc_q);
  sesum_k<<<384, 256, 0, stream>>>(y, bnacc_s, bnacc_q, bn_g[0], bn_b[0], bn_g[1], bn_b[1],
                                   bn_g[2], bn_b[2], se_acc);
  fuse_k<<<256, 256, 0, stream>>>(y, fwT, fuse_b, se_acc, bnacc_s, bnacc_q,
                                  bn_g[0], bn_b[0], bn_g[1], bn_b[1], bn_g[2], bn_b[2],
                                  se_w1[0], se_w1[1], se_w1[2], se_w2[0], se_w2[1], se_w2[2],
                                  xm, gp_conv_w, gp_conv_b, gp_bn_g, gp_bn_b,
                                  gp_se_w1, gp_se_w2, fuse_w, tmp, fstat);
  final_k<<<2048, 256, 0, stream>>>(tmp, fstat, fuse_bn_g, fuse_bn_b, out);
}

// Round 20
// 241.626 us; speedup vs baseline: 1.7263x; 1.0220x over previous
//
#include <hip/hip_runtime.h>
#include <hip/hip_bf16.h>
#include <math.h>

#define DEV __device__ __forceinline__

static constexpr int HW  = 4096;    // H*W
static constexpr int POS = 8192;    // B*H*W
static constexpr int SLAB = 6 * 64 * 4096;  // one ki-slab (floats)

typedef __attribute__((ext_vector_type(8)))  short short8;
typedef __attribute__((ext_vector_type(16))) float floatx16;
typedef __attribute__((ext_vector_type(4)))  unsigned int uint4v;

// ---------- B-spline basis (order 3); constant denominators -> mul by recip ----------
template<int G>
DEV void bsplines(float x, float* out /* G+3 values */) {
  const float h = 2.0f / (float)G;
  float knot[G + 7];
#pragma unroll
  for (int t = 0; t < G + 7; ++t) knot[t] = -1.0f + (float)(t - 3) * h;
  float bb[G + 6];
#pragma unroll
  for (int t = 0; t < G + 6; ++t) bb[t] = (x >= knot[t] && x < knot[t + 1]) ? 1.0f : 0.0f;
#pragma unroll
  for (int j = 1; j <= 3; ++j) {
    const float inv = (float)G / (2.0f * (float)j);   // 1/(j*h), compile-time
#pragma unroll
    for (int t = 0; t < G + 6 - j; ++t) {
      float left  = (x - knot[t]) * inv;
      float right = (knot[t + j + 1] - x) * inv;
      bb[t] = left * bb[t] + right * bb[t + 1];
    }
  }
#pragma unroll
  for (int t = 0; t < G + 3; ++t) out[t] = bb[t];
}

DEV float sigmoidf_(float x) { return 1.0f / (1.0f + __expf(-x)); }

DEV float block_reduce_256(float v, float* sb) {  // blockDim.x == 256
  __syncthreads();
#pragma unroll
  for (int off = 32; off > 0; off >>= 1) v += __shfl_down(v, off, 64);
  int lane = threadIdx.x & 63, wid = threadIdx.x >> 6;
  if (lane == 0) sb[wid] = v;
  __syncthreads();
  return sb[0] + sb[1] + sb[2] + sb[3];
}

// ================= prep bodies =================
// Fragment-major layouts (R5, proven):
//   W'[tap][s][half][lane*8]   (per tap: s<KC/16, 1024 elem per s)
//   F'[b][hs][s][wp][16]       (per row: s-major, 16 k per wp)
// R17 post-mortem: semlp fold into fuse_k cost +3.3us (256x redundant
// prologue) -> reverted to the measured-best R7 pipeline; vectorized wprep
// kept (verified in R17, neutral).

template<int CF>
DEV void wprep_body(const float* __restrict__ base_w, const float* __restrict__ spline_w,
                    __hip_bfloat16* __restrict__ Wt, int bid) {
  constexpr int KC = 64 * CF;        // KC % 8 == 0 for all branches
  int lin = (bid * 256 + threadIdx.x) * 8;  // (tap, o, ic) base; 8 elems/thread
  int ic = lin % KC;
  int rest = lin / KC;               // 8 consecutive ic stay in one (tap,o)
  int o = rest & 63, tap = rest >> 6;
  short8 vout;
#pragma unroll
  for (int e = 0; e < 8; ++e) {
    int ice = ic + e;
    int c = ice % CF, i = ice / CF;
    float v = (c == 0) ? base_w[(o * 64 + i) * 9 + tap]
                       : spline_w[((o * 64 + i) * 9 + tap) * (CF - 1) + (c - 1)];
    __hip_bfloat16 bv = __float2bfloat16(v);
    vout[e] = *reinterpret_cast<short*>(&bv);
  }
  // dst: s=ic>>4, q=(ic&15)>>3 const across the 8; r=0..7 consecutive
  int s = ic >> 4, q = (ic & 15) >> 3, hh = o >> 5;
  int l = q * 32 + (o & 31);
  *(short8*)(Wt + (size_t)tap * (64 * KC) + s * 1024 + hh * 512 + l * 8) = vout;
}

template<int G>
DEV void c0r_body(int ki, const float* __restrict__ sw, float* __restrict__ out,
                  float* shmem /* >=256 floats */) {
  constexpr int NB = G + 3;
  int o = threadIdx.x & 63, part = threadIdx.x >> 6;  // 4 parts over i
  float b0[NB];
  bsplines<G>(0.0f, b0);
  float s = 0.0f;
  for (int kj = 0; kj < 3; ++kj) {
    int tap = ki * 3 + kj;
    for (int i = part * 16; i < part * 16 + 16; ++i) {
      const float* p = sw + ((size_t)(o * 64 + i) * 9 + tap) * NB;
#pragma unroll
      for (int c = 0; c < NB; ++c) s += p[c] * b0[c];
    }
  }
  shmem[part * 64 + o] = s;
  __syncthreads();
  if (part == 0)
    out[ki * 64 + o] = shmem[o] + shmem[64 + o] + shmem[128 + o] + shmem[192 + o];
}

// ---- merged interior features: one x load feeds all 3 branches ----
template<int G, int RB>
DEV void feat_stage(float xv, float s, __hip_bfloat16* lds, int ws, int i) {
  constexpr int CF = G + 4;
  constexpr int RS = 64 * CF + 16;    // padded region stride (bf16)
  float bas[G + 3];
  bsplines<G>(xv, bas);
  __hip_bfloat16* d = lds + RB + ws * RS + i * CF;
  d[0] = __float2bfloat16(s);
#pragma unroll
  for (int c = 1; c < CF; ++c) d[c] = __float2bfloat16(bas[c - 1]);
}

template<int CF, int D, int RBu>
DEV void feat_copy(__hip_bfloat16* __restrict__ F, int b, int h, int wg, const uint4v* l) {
  constexpr int WP = 64 + 2 * D;
  constexpr int KC = 64 * CF;
  uint4v* g = (uint4v*)(F + (size_t)(b * 64 + h) * WP * KC);
  for (int t = threadIdx.x; t < 32 * CF; t += 256) {
    int sc = t >> 3, r = t & 7, wl = r >> 1, k4 = r & 1;
    g[(size_t)(sc * WP + D + wg * 4 + wl) * 2 + k4] = l[RBu + wl * (8 * CF + 2) + sc * 2 + k4];
  }
}

DEV void feat_interior(const float* __restrict__ x, __hip_bfloat16* F0, __hip_bfloat16* F1,
                       __hip_bfloat16* F2, int bid, __hip_bfloat16* lds) {
  int tid = threadIdx.x;
  int ws = tid & 3, i = tid >> 2;
  int wg = bid & 15, h = (bid >> 4) & 63, b = bid >> 10;
  int w = wg * 4 + ws;
  float xv = x[((size_t)(b * 64 + i) * 64 + h) * 64 + w];   // always in-bounds
  float s = xv * sigmoidf_(xv);
  feat_stage<3, 0>(xv, s, lds, ws, i);      // CF=7,  RS=464
  feat_stage<6, 1856>(xv, s, lds, ws, i);   // CF=10, RS=656
  feat_stage<9, 4480>(xv, s, lds, ws, i);   // CF=13, RS=848
  __syncthreads();
  const uint4v* l = (const uint4v*)lds;
  feat_copy<7, 6, 0>(F0, b, h, wg, l);
  feat_copy<10, 12, 232>(F1, b, h, wg, l);
  feat_copy<13, 18, 560>(F2, b, h, wg, l);
}

// ---- constant halo fill: features of x=0 at wp in [0,D) u [64+D,WP) ----
template<int G, int D>
DEV void halo_body(__hip_bfloat16* __restrict__ F, int bidl, __hip_bfloat16* ldsb) {
  constexpr int CF = G + 4;
  constexpr int WP = 64 + 2 * D;
  constexpr int KC = 64 * CF;
  constexpr int PW = 8 * CF;      // uint4 per (row, halo-wp)
  constexpr int D2 = 2 * D;
  int tid = threadIdx.x;
  float bas0[G + 3];
  bsplines<G>(0.0f, bas0);        // bitwise-identical to interior xv=0 path
  for (int k = tid; k < KC; k += 256) {
    int c = k % CF;
    float v = 0.0f;               // c==0: silu(0)=0
#pragma unroll
    for (int cc = 1; cc < CF; ++cc) v = (c == cc) ? bas0[cc - 1] : v;
    ldsb[k] = __float2bfloat16(v);
  }
  __syncthreads();
  const uint4v* l = (const uint4v*)ldsb;
  uint4v* g = (uint4v*)F;
#pragma unroll
  for (int u = 0; u < 16; ++u) {
    int t = bidl * 4096 + u * 256 + tid;
    int rw = t / PW, r2 = t - rw * PW;
    int sc = r2 >> 1, k4 = r2 & 1;
    int row = rw / D2, wj = rw - row * D2;
    int wp = (wj < D) ? wj : 64 + wj;
    g[(size_t)row * (WP * KC / 8) + (size_t)(sc * WP + wp) * 2 + k4] = l[sc * 2 + k4];
  }
}

// ========== merged prep + features (data-independent, disjoint bid ranges) ==========
__global__ void prepfeat_k(const float* __restrict__ x,
                           __hip_bfloat16* F0, __hip_bfloat16* F1, __hip_bfloat16* F2,
                           const float* bw0, const float* sw0, const float* bw1,
                           const float* sw1, const float* bw2, const float* sw2,
                           __hip_bfloat16* W0, __hip_bfloat16* W1, __hip_bfloat16* W2,
                           float* C0r, const float* fuse_w, float* fwT,
                           float* xm, float* accz /* 896 floats */) {
  __shared__ uint4v ldsq[984];                  // 3 regions: 4*(464+656+848) bf16 = 15744B
  __shared__ float shmem[256];                  // prep reductions
  __hip_bfloat16* lds = (__hip_bfloat16*)ldsq;
  int bid = blockIdx.x, tid = threadIdx.x;
  if (bid < 2048)      { feat_interior(x, F0, F1, F2, bid, lds); return; }
  else if (bid < 2069) { halo_body<3, 6>(F0, bid - 2048, lds); return; }   // 21 blocks
  else if (bid < 2129) { halo_body<6, 12>(F1, bid - 2069, lds); return; }  // 60 blocks
  else if (bid < 2246) { halo_body<9, 18>(F2, bid - 2129, lds); return; }  // 117 blocks
  int pb = bid - 2246;                          // [0, 726) prep blocks
  if (pb < 126)       { wprep_body<7>(bw0, sw0, W0, pb); }
  else if (pb < 306)  { wprep_body<10>(bw1, sw1, W1, pb - 126); }
  else if (pb < 540)  { wprep_body<13>(bw2, sw2, W2, pb - 306); }
  else if (pb < 549) {
    int idx = pb - 540, br = idx / 3, ki = idx % 3;
    if (br == 0)      c0r_body<3>(ki, sw0, C0r, shmem);
    else if (br == 1) c0r_body<6>(ki, sw1, C0r + 192, shmem);
    else              c0r_body<9>(ki, sw2, C0r + 384, shmem);
  } else if (pb < 597) {  // fuse_w transpose (branch part)
    int lin = (pb - 549) * 256 + tid;  // [0, 12288)
    int o = lin & 63, i2 = lin >> 6;
    fwT[i2 * 64 + o] = fuse_w[o * 256 + i2];
  } else if (pb < 725) {  // x mean per (b,i)
    int bi = pb - 597;
    const float* p = x + (size_t)bi * HW;
    float s = 0.0f;
    for (int t = tid; t < HW; t += 256) s += p[t];
    s = block_reduce_256(s, shmem);
    if (tid == 0) xm[bi] = s * (1.0f / HW);
  } else {  // zero accumulators: fstat[128] | bnacc_s[192] | bnacc_q[192] | se_acc[384]
    for (int t = tid; t < 896; t += 256) accz[t] = 0.0f;
  }
}

// ============ KAN conv: R7 ki-centric (proven 44us) — byte-identical ============
DEV floatx16 mfma_bf16(short8 a, short8 b, floatx16 c) {
  return __builtin_amdgcn_mfma_f32_32x32x16_bf16(a, b, c, 0, 0, 0);
}

template<int CF, int DD>
DEV void conv_dev(int ki, int b, int hp, const short* __restrict__ F,
                  const short* __restrict__ W, const float* __restrict__ C0r,
                  float* __restrict__ ypart, int br, float* __restrict__ red) {
  constexpr int KC = 64 * CF;
  constexpr int WP = 64 + 2 * DD;
  int wid = threadIdx.x >> 6;       // 0..5
  int wv  = wid & 1;                // source-row select
  int kjw = wid >> 1;               // kj tap owned by this wave
  int lane = threadIdx.x & 63;
  int lr = lane & 31, lq = lane >> 5;
  int hs = hp * 2 + wv;             // source row (always valid)
  int h_out = hs - (ki - 1) * DD;   // output row this source feeds for this ki
  bool valid = (h_out >= 0 && h_out < 64);
  int h_tgt = valid ? h_out : (h_out < 0 ? h_out + 64 : h_out - 64);  // mirror: C0 rows
  float* yb = ypart + (size_t)ki * SLAB + ((size_t)((br * 2 + b) * 64 + h_tgt)) * 4096;

  floatx16 acc[2][2];
#pragma unroll
  for (int ot = 0; ot < 2; ++ot)
#pragma unroll
    for (int wh = 0; wh < 2; ++wh)
#pragma unroll
      for (int r = 0; r < 16; ++r) acc[ot][wh][r] = 0.0f;

  if (valid) {
    // fragment-major bases: every load is base + s*const + lane-contiguous 16B
    const short* wl_ = W + (size_t)(ki * 3 + kjw) * (64 * KC) + lane * 8;
    const short* fB  = F + (size_t)(b * 64 + hs) * WP * KC
                         + (kjw * DD + lr) * 16 + lq * 8;
#pragma unroll 4
    for (int s = 0; s < 4 * CF; ++s) {   // 16-K per step
      short8 a0 = *(const short8*)(wl_ + s * 1024);
      short8 a1 = *(const short8*)(wl_ + s * 1024 + 512);
      short8 b0 = *(const short8*)(fB + s * (WP * 16));
      short8 b1 = *(const short8*)(fB + s * (WP * 16) + 512);
      acc[0][0] = mfma_bf16(a0, b0, acc[0][0]);
      acc[0][1] = mfma_bf16(a0, b1, acc[0][1]);
      acc[1][0] = mfma_bf16(a1, b0, acc[1][0]);
      acc[1][1] = mfma_bf16(a1, b1, acc[1][1]);
    }
  }

  // ---- reduce the 3 kj partials through LDS (stride 65: conflict-free) ----
  float* slot = red + (size_t)wv * (64 * 65) + lane * 65;
  if (kjw == 2 && valid) {
#pragma unroll
    for (int ot = 0; ot < 2; ++ot)
#pragma unroll
      for (int wh = 0; wh < 2; ++wh)
#pragma unroll
        for (int r = 0; r < 16; ++r) slot[(ot * 2 + wh) * 16 + r] = acc[ot][wh][r];
  }
  __syncthreads();
  if (kjw == 1 && valid) {
#pragma unroll
    for (int ot = 0; ot < 2; ++ot)
#pragma unroll
      for (int wh = 0; wh < 2; ++wh)
#pragma unroll
        for (int r = 0; r < 16; ++r) {
          int idx = (ot * 2 + wh) * 16 + r;
          slot[idx] += acc[ot][wh][r];
        }
  }
  __syncthreads();
  if (kjw != 0) return;

  if (!valid) {  // paired output row's source is OOB: constant C0 contribution
    const float* c0 = C0r + (br * 3 + ki) * 64;
#pragma unroll
    for (int wh = 0; wh < 2; ++wh) {
      int w = wh * 32 + lr;
#pragma unroll
      for (int ot = 0; ot < 2; ++ot)
#pragma unroll
        for (int r = 0; r < 16; ++r) {
          int o = (r & 3) + 8 * (r >> 2) + 4 * lq + 32 * ot;
          yb[(size_t)o * 64 + w] = c0[o];
        }
    }
    return;
  }

#pragma unroll
  for (int ot = 0; ot < 2; ++ot)
#pragma unroll
    for (int wh = 0; wh < 2; ++wh) {
      int w = wh * 32 + lr;
#pragma unroll
      for (int r = 0; r < 16; ++r) {
        int o = (r & 3) + 8 * (r >> 2) + 4 * lq + 32 * ot;
        yb[(size_t)o * 64 + w] = acc[ot][wh][r] + slot[(ot * 2 + wh) * 16 + r];
      }
    }
}

__global__ __launch_bounds__(384) void conv_all_k(
    const short* __restrict__ F0, const short* __restrict__ F1, const short* __restrict__ F2,
    const short* __restrict__ W0, const short* __restrict__ W1, const short* __restrict__ W2,
    const float* __restrict__ C0r, float* __restrict__ ypart) {
  __shared__ float red[2 * 64 * 65];    // 33.3 KB partial-acc reduction buffer
  // XCD swizzle: ki-siblings at bid, bid+8, bid+16 -> same XCD (bid % 8 fixed)
  int bid = blockIdx.x;                 // [0,576)
  int e  = bid & 7;
  int t  = bid >> 3;                    // [0,72)
  int ki = t % 3;
  int m  = (t / 3) * 8 + e;             // [0,192) combo (br,b,hp)
  int br = m >> 6, b = (m >> 5) & 1, hp = m & 31;
  if (br == 0)      conv_dev<7, 6>(ki, b, hp, F0, W0, C0r, ypart, 0, red);
  else if (br == 1) conv_dev<10, 12>(ki, b, hp, F1, W1, C0r, ypart, 1, red);
  else              conv_dev<13, 18>(ki, b, hp, F2, W2, C0r, ypart, 2, red);
}

// ====== reduce 3 ki-slabs into slab0 + atomic per-(br,o) BN partials ======
__global__ void rb_k(float* __restrict__ yp, float* __restrict__ bnacc_s,
                     float* __restrict__ bnacc_q) {
  int bid = blockIdx.x;                 // [0,1536) = bb(6) x chunk(256)
  int bb = bid / 256, chunk = bid % 256;
  int br = bb >> 1;
  int tid = threadIdx.x;
  size_t base = (size_t)bb * 262144 + chunk * 1024 + tid * 4;
  float4 v = *(const float4*)(yp + base);
#pragma unroll
  for (int s2 = 1; s2 < 3; ++s2) {
    float4 u = *(const float4*)(yp + base + (size_t)s2 * SLAB);
    v.x += u.x; v.y += u.y; v.z += u.z; v.w += u.w;
  }
  *(float4*)(yp + base) = v;
  float s = v.x + v.y + v.z + v.w;
  float q = v.x * v.x + v.y * v.y + v.z * v.z + v.w * v.w;
  s += __shfl_down(s, 8, 16); s += __shfl_down(s, 4, 16);
  s += __shfl_down(s, 2, 16); s += __shfl_down(s, 1, 16);
  q += __shfl_down(q, 8, 16); q += __shfl_down(q, 4, 16);
  q += __shfl_down(q, 2, 16); q += __shfl_down(q, 1, 16);
  if ((tid & 15) == 0) {
    int o = (chunk * 16 + (tid >> 4)) & 63;
    atomicAdd(&bnacc_s[br * 64 + o], s);
    atomicAdd(&bnacc_q[br * 64 + o], q);
  }
}

// ====== SE pre-sum: atomic sum over (h,w) of relu(bn(y)) per (bb,o) ======
__global__ void sesum_k(const float* __restrict__ y, const float* __restrict__ bnacc_s,
                        const float* __restrict__ bnacc_q,
                        const float* g0, const float* b0p, const float* g1, const float* b1p,
                        const float* g2, const float* b2p, float* __restrict__ se_acc) {
  int bid = blockIdx.x;                 // [0,384) = bb(6) x h(64)
  int bb = bid >> 6, h = bid & 63;
  int br = bb >> 1;
  int tid = threadIdx.x;
  int o = tid >> 2, wq = tid & 3;
  const float* gptr = (br == 0) ? g0 : ((br == 1) ? g1 : g2);
  const float* bptr = (br == 0) ? b0p : ((br == 1) ? b1p : b2p);
  float mu = bnacc_s[br * 64 + o] * (1.0f / POS);
  float var = bnacc_q[br * 64 + o] * (1.0f / POS) - mu * mu;
  float kk = gptr[o] / sqrtf(var + 1e-5f);
  float cc = bptr[o] - mu * kk;
  const float* row = y + (size_t)bb * 262144 + (size_t)h * 4096 + o * 64 + wq * 16;
  float s = 0.0f;
#pragma unroll
  for (int j = 0; j < 4; ++j) {
    float4 v = *(const float4*)(row + j * 4);
    float a;
    a = v.x * kk + cc; s += (a > 0.0f) ? a : 0.0f;
    a = v.y * kk + cc; s += (a > 0.0f) ? a : 0.0f;
    a = v.z * kk + cc; s += (a > 0.0f) ? a : 0.0f;
    a = v.w * kk + cc; s += (a > 0.0f) ? a : 0.0f;
  }
  s += __shfl_down(s, 2, 4);
  s += __shfl_down(s, 1, 4);
  if (wq == 0) atomicAdd(&se_acc[bb * 64 + o], s);
}

// ============ SE MLP fold (blocks 0-5) + global-pool branch (block 6) ============
__global__ void semlp_gp_k(const float* __restrict__ se_acc,
                           const float* __restrict__ bnacc_s, const float* __restrict__ bnacc_q,
                           const float* g0, const float* b0p, const float* g1, const float* b1p,
                           const float* g2, const float* b2p,
                           const float* w10, const float* w11, const float* w12,
                           const float* w20, const float* w21, const float* w22,
                           float* __restrict__ A1, float* __restrict__ A0,
                           const float* __restrict__ xm, const float* __restrict__ gw,
                           const float* __restrict__ gb, const float* __restrict__ bng,
                           const float* __restrict__ bnb, const float* __restrict__ gpw1,
                           const float* __restrict__ gpw2, const float* __restrict__ fuse_w,
                           float* __restrict__ fuse_gp) {
  __shared__ float sm[64];
  __shared__ float g0s[2][64], gp1s[2][64], gpvs[2][64];
  int tid = threadIdx.x;
  if (blockIdx.x < 6) {
    int bb = blockIdx.x, br = bb >> 1;
    const float* w1 = (br == 0) ? w10 : ((br == 1) ? w11 : w12);
    const float* w2 = (br == 0) ? w20 : ((br == 1) ? w21 : w22);
    const float* gptr = (br == 0) ? g0 : ((br == 1) ? g1 : g2);
    const float* bptr = (br == 0) ? b0p : ((br == 1) ? b1p : b2p);
    if (tid < 64) sm[tid] = se_acc[bb * 64 + tid] * (1.0f / HW);
    __syncthreads();
    if (tid < 64) {
      int o = tid;
      float z[4];
#pragma unroll
      for (int j = 0; j < 4; ++j) {
        float s = 0.0f;
        for (int c2 = 0; c2 < 64; ++c2) s += sm[c2] * w1[j * 64 + c2];
        z[j] = (s > 0.0f) ? s : 0.0f;
      }
      float t = 0.0f;
#pragma unroll
      for (int j = 0; j < 4; ++j) t += z[j] * w2[o * 4 + j];
      t = sigmoidf_(t);
      float mu = bnacc_s[br * 64 + o] * (1.0f / POS);
      float var = bnacc_q[br * 64 + o] * (1.0f / POS) - mu * mu;
      float kk = gptr[o] / sqrtf(var + 1e-5f);
      float cc = bptr[o] - mu * kk;
      A1[bb * 64 + o] = kk * t;  // relu(x)*t == relu(x*t), t>0
      A0[bb * 64 + o] = cc * t;
    }
  } else {  // global-pool branch, fully folded into fuse_gp[b][o]
    int b = tid >> 6, o = tid & 63;
    float gv = gb[o];
    for (int i = 0; i < 64; ++i) gv += xm[b * 64 + i] * gw[o * 64 + i];
    g0s[b][o] = gv;
    __syncthreads();
    float mu = 0.5f * (g0s[0][o] + g0s[1][o]);
    float df = g0s[0][o] - g0s[1][o];
    float var = 0.25f * df * df;
    float v = (gv - mu) / sqrtf(var + 1e-5f) * bng[o] + bnb[o];
    v = (v > 0.0f) ? v : 0.0f;
    gp1s[b][o] = v;
    __syncthreads();
    float z[4];
#pragma unroll
    for (int j = 0; j < 4; ++j) {
      float s = 0.0f;
      for (int c2 = 0; c2 < 64; ++c2) s += gp1s[b][c2] * gpw1[j * 64 + c2];
      z[j] = (s > 0.0f) ? s : 0.0f;
    }
    float t = 0.0f;
#pragma unroll
    for (int j = 0; j < 4; ++j) t += z[j] * gpw2[o * 4 + j];
    t = sigmoidf_(t);
    gpvs[b][o] = v * t;
    __syncthreads();
    float fg = 0.0f;
    for (int c2 = 0; c2 < 64; ++c2) fg += fuse_w[o * 256 + 192 + c2] * gpvs[b][c2];
    fuse_gp[b * 64 + o] = fg;
  }
}

// ============ fuse GEMM (w-split, 256 blocks) + atomic BN-stat partials ============
__global__ __launch_bounds__(256) void fuse_k(
    const float* __restrict__ y, const float* __restrict__ A1, const float* __restrict__ A0,
    const float* __restrict__ fwT, const float* __restrict__ fb, const float* __restrict__ fgp,
    float* __restrict__ tmp, float* __restrict__ fstat) {
  int bid = blockIdx.x;                 // [0,256): (b, h, w-half)
  int b = bid >> 7, h = (bid >> 1) & 63, wh = bid & 1;
  int tid = threadIdx.x;
  int wg = tid & 7, og = tid >> 3;      // 8 w-groups x 32 o-groups
  int w0 = wg * 4, o0 = og * 2;
  float acc[2][4] = {};
  __shared__ float As[64][32];
  __shared__ float Ws[64][64];
  for (int br = 0; br < 3; ++br) {
#pragma unroll
    for (int m = 0; m < 8; ++m) {       // stage As: 64 oc x 32 w
      int lin = tid + m * 256;
      int oc = lin >> 5, wl = lin & 31;
      float v = y[(size_t)(br * 2 + b) * 262144 + (size_t)h * 4096 + oc * 64 + wh * 32 + wl];
      float a1 = A1[(br * 2 + b) * 64 + oc], a0 = A0[(br * 2 + b) * 64 + oc];
      v = v * a1 + a0;
      As[oc][wl] = (v > 0.0f) ? v : 0.0f;
    }
#pragma unroll
    for (int m = 0; m < 16; ++m) {      // stage Ws: 64 oc x 64 o
      int lin = tid + m * 256;
      int oc = lin >> 6, ol = lin & 63;
      Ws[oc][ol] = fwT[(br * 64 + oc) * 64 + ol];
    }
    __syncthreads();
#pragma unroll 8
    for (int ict = 0; ict < 64; ++ict) {
      float4 a = *reinterpret_cast<const float4*>(&As[ict][w0]);
      float2 wv = *reinterpret_cast<const float2*>(&Ws[ict][o0]);
      acc[0][0] += wv.x * a.x; acc[0][1] += wv.x * a.y; acc[0][2] += wv.x * a.z; acc[0][3] += wv.x * a.w;
      acc[1][0] += wv.y * a.x; acc[1][1] += wv.y * a.y; acc[1][2] += wv.y * a.z; acc[1][3] += wv.y * a.w;
    }
    __syncthreads();
  }
  float* tp = tmp + (size_t)(b * 64 + h) * 4096 + wh * 32;
  float ps[2], pq[2];
#pragma unroll
  for (int oo = 0; oo < 2; ++oo) {
    int o = o0 + oo;
    float bias = fb[o] + fgp[b * 64 + o];
    float4 v = make_float4(acc[oo][0] + bias, acc[oo][1] + bias,
                           acc[oo][2] + bias, acc[oo][3] + bias);
    *reinterpret_cast<float4*>(&tp[o * 64 + w0]) = v;
    ps[oo] = v.x + v.y + v.z + v.w;
    pq[oo] = v.x * v.x + v.y * v.y + v.z * v.z + v.w * v.w;
  }
  __syncthreads();
#pragma unroll
  for (int oo = 0; oo < 2; ++oo) { As[o0 + oo][wg] = ps[oo]; Ws[o0 + oo][wg] = pq[oo]; }
  __syncthreads();
  if (tid < 64) {
    float s = 0.0f, q = 0.0f;
#pragma unroll
    for (int r = 0; r < 8; ++r) { s += As[tid][r]; q += Ws[tid][r]; }
    atomicAdd(&fstat[tid], s);
    atomicAdd(&fstat[64 + tid], q);
  }
}

// ---------- final BN+relu, write (B,Co,H,W) ----------
__global__ void final_k(const float* __restrict__ tmp, const float* __restrict__ fstat,
                        const float* __restrict__ g, const float* __restrict__ bb,
                        float* __restrict__ out) {
  int lin = blockIdx.x * 256 + threadIdx.x;  // [0, 524288)
  int w = lin & 63, h2 = (lin >> 6) & 63, o = (lin >> 12) & 63, b = lin >> 18;
  float v = tmp[((size_t)(b * 64 + h2) * 64 + o) * 64 + w];
  float m = fstat[o] * (1.0f / POS);
  float var = fstat[64 + o] * (1.0f / POS) - m * m;
  float kk = g[o] / sqrtf(var + 1e-5f);
  float r = (v - m) * kk + bb[o];
  out[lin] = (r > 0.0f) ? r : 0.0f;
}

extern "C" void kernel_launch(void* const* d_in, const int* in_sizes, int n_in,
                              void* d_out, int out_size, void* d_ws, size_t ws_size,
                              hipStream_t stream) {
  const float* x = (const float*)d_in[0];
  const float* base_w[3]   = {(const float*)d_in[1],  (const float*)d_in[7],  (const float*)d_in[13]};
  const float* spline_w[3] = {(const float*)d_in[2],  (const float*)d_in[8],  (const float*)d_in[14]};
  const float* bn_g[3]     = {(const float*)d_in[3],  (const float*)d_in[9],  (const float*)d_in[15]};
  const float* bn_b[3]     = {(const float*)d_in[4],  (const float*)d_in[10], (const float*)d_in[16]};
  const float* se_w1[3]    = {(const float*)d_in[5],  (const float*)d_in[11], (const float*)d_in[17]};
  const float* se_w2[3]    = {(const float*)d_in[6],  (const float*)d_in[12], (const float*)d_in[18]};
  const float* gp_conv_w = (const float*)d_in[19];
  const float* gp_conv_b = (const float*)d_in[20];
  const float* gp_bn_g   = (const float*)d_in[21];
  const float* gp_bn_b   = (const float*)d_in[22];
  const float* gp_se_w1  = (const float*)d_in[23];
  const float* gp_se_w2  = (const float*)d_in[24];
  const float* fuse_w    = (const float*)d_in[25];
  const float* fuse_b    = (const float*)d_in[26];
  const float* fuse_bn_g = (const float*)d_in[27];
  const float* fuse_bn_b = (const float*)d_in[28];
  float* out = (float*)d_out;

  char* wsp = (char*)d_ws;
  auto alloc = [&](size_t bytes) -> char* {
    char* p = wsp;
    wsp += (bytes + 255) & ~(size_t)255;
    return p;
  };
  __hip_bfloat16* F0 = (__hip_bfloat16*)alloc((size_t)2 * 64 * 76 * 448 * 2);
  __hip_bfloat16* F1 = (__hip_bfloat16*)alloc((size_t)2 * 64 * 88 * 640 * 2);
  __hip_bfloat16* F2 = (__hip_bfloat16*)alloc((size_t)2 * 64 * 100 * 832 * 2);
  __hip_bfloat16* W0 = (__hip_bfloat16*)alloc((size_t)9 * 64 * 448 * 2);
  __hip_bfloat16* W1 = (__hip_bfloat16*)alloc((size_t)9 * 64 * 640 * 2);
  __hip_bfloat16* W2 = (__hip_bfloat16*)alloc((size_t)9 * 64 * 832 * 2);
  float* C0r   = (float*)alloc((size_t)3 * 3 * 64 * 4);
  float* ypart = (float*)alloc((size_t)3 * SLAB * 4);   // 3 ki-slabs; slab0 -> y
  float* y     = ypart;
  float* tmp   = ypart + SLAB;   // slab1 dead after rb_k -> reuse
  float* A1  = (float*)alloc(384 * 4);
  float* A0  = (float*)alloc(384 * 4);
  float* xm  = (float*)alloc(128 * 4);
  float* fgp = (float*)alloc(128 * 4);
  float* fwT = (float*)alloc((size_t)12288 * 4);
  float* accz = (float*)alloc(896 * 4);  // fstat[128] | bnacc_s[192] | bnacc_q[192] | se_acc[384]
  float* fstat   = accz;
  float* bnacc_s = accz + 128;
  float* bnacc_q = accz + 320;
  float* se_acc  = accz + 512;

  prepfeat_k<<<2972, 256, 0, stream>>>(x, F0, F1, F2,
                                       base_w[0], spline_w[0], base_w[1], spline_w[1],
                                       base_w[2], spline_w[2], W0, W1, W2, C0r,
                                       fuse_w, fwT, xm, accz);
  conv_all_k<<<576, 384, 0, stream>>>(
      (const short*)F0, (const short*)F1, (const short*)F2,
      (const short*)W0, (const short*)W1, (const short*)W2, C0r, ypart);
  rb_k<<<1536, 256, 0, stream>>>(ypart, bnacc_s, bnacc_q);
  sesum_k<<<384, 256, 0, stream>>>(y, bnacc_s, bnacc_q, bn_g[0], bn_b[0], bn_g[1], bn_b[1],
                                   bn_g[2], bn_b[2], se_acc);
  semlp_gp_k<<<7, 128, 0, stream>>>(se_acc, bnacc_s, bnacc_q, bn_g[0], bn_b[0], bn_g[1], bn_b[1],
                                    bn_g[2], bn_b[2], se_w1[0], se_w1[1], se_w1[2],
                                    se_w2[0], se_w2[1], se_w2[2], A1, A0,
                                    xm, gp_conv_w, gp_conv_b, gp_bn_g, gp_bn_b,
                                    gp_se_w1, gp_se_w2, fuse_w, fgp);
  fuse_k<<<256, 256, 0, stream>>>(y, A1, A0, fwT, fuse_b, fgp, tmp, fstat);
  final_k<<<2048, 256, 0, stream>>>(tmp, fstat, fuse_bn_g, fuse_bn_b, out);
}